// Round 11
// baseline (113.718 us; speedup 1.0000x reference)
//
#include <hip/hip_runtime.h>
#include <math.h>

// Problem constants (b=4, n=m=l=4096, d=512, fft_len=8192, t_len=2l-2=8190)
#define N_FFT   8192
#define SEQ     4096
#define NCH     512
#define TLEN    8190

__device__ __forceinline__ float2 cmul(float2 a, float2 b) {
    return make_float2(a.x * b.x - a.y * b.y, a.x * b.y + a.y * b.x);
}
__device__ __forceinline__ float2 cmulj(float2 a, float2 b) {   // a * conj(b)
    return make_float2(a.x * b.x + a.y * b.y, a.y * b.x - a.x * b.y);
}
__device__ __forceinline__ float2 cadd(float2 a, float2 b) {
    return make_float2(a.x + b.x, a.y + b.y);
}
__device__ __forceinline__ float2 csub(float2 a, float2 b) {
    return make_float2(a.x - b.x, a.y - b.y);
}

// W32^j = exp(-2*pi*i*j/32), j in [0,16)
constexpr float W32C[16] = {
    1.0f, 0.9807852804032304f, 0.9238795325112867f, 0.8314696123025452f,
    0.7071067811865476f, 0.5555702330196023f, 0.3826834323650898f, 0.1950903220161283f,
    0.0f, -0.1950903220161282f, -0.3826834323650897f, -0.5555702330196020f,
    -0.7071067811865475f, -0.8314696123025453f, -0.9238795325112867f, -0.9807852804032304f
};
constexpr float W32S[16] = {
    -0.0f, -0.1950903220161283f, -0.3826834323650898f, -0.5555702330196022f,
    -0.7071067811865476f, -0.8314696123025452f, -0.9238795325112867f, -0.9807852804032304f,
    -1.0f, -0.9807852804032304f, -0.9238795325112867f, -0.8314696123025453f,
    -0.7071067811865476f, -0.5555702330196022f, -0.3826834323650899f, -0.1950903220161286f
};

constexpr int BREV5[32] = {0,16,8,24,4,20,12,28,2,18,10,26,6,22,14,30,
                           1,17,9,25,5,21,13,29,3,19,11,27,7,23,15,31};
constexpr int BREV4[16] = {0,8,4,12,2,10,6,14,1,9,5,13,3,11,7,15};

__device__ __forceinline__ int brev3i(int b) {
    return ((b & 1) << 2) | (b & 2) | ((b & 4) >> 2);
}

// ---------------------------------------------------------------- reg FFTs ---
__device__ __forceinline__ void fft32_dif(float2 a[32]) {
#pragma unroll
    for (int s = 4; s >= 0; --s) {
        const int h = 1 << s;
#pragma unroll
        for (int g = 0; g < 32; g += 2 * h) {
#pragma unroll
            for (int i = 0; i < h; ++i) {
                float2 x0 = a[g + i], x1 = a[g + i + h];
                a[g + i] = cadd(x0, x1);
                float2 w = make_float2(W32C[i << (4 - s)], W32S[i << (4 - s)]);
                a[g + i + h] = cmul(csub(x0, x1), w);
            }
        }
    }
}

__device__ __forceinline__ void fft16_dif(float2 a[16]) {
#pragma unroll
    for (int s = 3; s >= 0; --s) {
        const int h = 1 << s;
#pragma unroll
        for (int g = 0; g < 16; g += 2 * h) {
#pragma unroll
            for (int i = 0; i < h; ++i) {
                float2 x0 = a[g + i], x1 = a[g + i + h];
                a[g + i] = cadd(x0, x1);
                float2 w = make_float2(W32C[i << (4 - s)], W32S[i << (4 - s)]);
                a[g + i + h] = cmul(csub(x0, x1), w);
            }
        }
    }
}

__device__ __forceinline__ void ifft16_dit(float2 a[16]) {
#pragma unroll
    for (int s = 0; s <= 3; ++s) {
        const int h = 1 << s;
#pragma unroll
        for (int g = 0; g < 16; g += 2 * h) {
#pragma unroll
            for (int i = 0; i < h; ++i) {
                float2 w = make_float2(W32C[i << (4 - s)], -W32S[i << (4 - s)]);
                float2 t = cmul(a[g + i + h], w);
                float2 x0 = a[g + i];
                a[g + i] = cadd(x0, t);
                a[g + i + h] = csub(x0, t);
            }
        }
    }
}

__device__ __forceinline__ void fft8_dif(float2 a[8]) {
#pragma unroll
    for (int s = 2; s >= 0; --s) {
        const int h = 1 << s;
#pragma unroll
        for (int g = 0; g < 8; g += 2 * h) {
#pragma unroll
            for (int i = 0; i < h; ++i) {
                float2 x0 = a[g + i], x1 = a[g + i + h];
                a[g + i] = cadd(x0, x1);
                int e = (i << (2 - s)) << 2;   // W8^m = W32^{4m}
                float2 w = make_float2(W32C[e], W32S[e]);
                a[g + i + h] = cmul(csub(x0, x1), w);
            }
        }
    }
}

// bank-conflict-reduced LDS slot, 32-row layout (tfft)
__device__ __forceinline__ int SLOT(int r, int c) {
    return (r << 8) + (c ^ ((c >> 4) & 7) ^ ((r & 1) << 3));
}
// LDS slot of frequency bin q after tfft forward stage C
__device__ __forceinline__ int ZADDR(int q) {
    return SLOT(q & 31, (((q >> 5) & 31) << 3) + brev3i((q >> 10) & 7));
}
// 16-row layout (conv)
__device__ __forceinline__ int SLOT16(int r, int c) {
    return (r << 8) + (c ^ ((c >> 4) & 7) ^ ((r & 1) << 3));
}

// ---------------------------------------------------------------- twiddles ---
__global__ __launch_bounds__(256) void twiddle_init(float2* __restrict__ tw) {
    int k = blockIdx.x * 256 + threadIdx.x;
    double th = -2.0 * 3.14159265358979323846 * (double)k / (double)N_FFT;
    tw[k] = make_float2((float)cos(th), (float)sin(th));
}

// ---------------------------------------------------------------- transposes -
// Fused input transposes.
// bid < 1024:  x[b][n][d] -> xT[pb][d][n]  (64n x 64d tiles, float4 loads)
// bid >= 1024: t[n][d] -> tT[dp][n] (zero-padded to 8192)
__global__ __launch_bounds__(256) void transpose_in(const float* __restrict__ x,
                                                    const float* __restrict__ t,
                                                    float2* __restrict__ xT,
                                                    float2* __restrict__ tT) {
    __shared__ float tX[64][65], tY[64][65];
    const int tid = threadIdx.x;
    if (blockIdx.x < 1024) {
        const int bid = blockIdx.x;        // [pb:2][dt:8][nt:64]
        const int pb = bid >> 9;
        const int dt = (bid >> 6) & 7;
        const int nt = bid & 63;
        const int d0 = dt << 6, n0 = nt << 6;
        const float* x0 = x + (size_t)(2 * pb) * SEQ * NCH;
        const float* x1 = x0 + (size_t)SEQ * NCH;
        {
            const int c4 = tid & 15, r16 = tid >> 4;   // 16 float4 cols, 16 rows
#pragma unroll
            for (int it = 0; it < 4; ++it) {
                int row = r16 + (it << 4);
                size_t off = (size_t)(n0 + row) * NCH + d0 + (c4 << 2);
                float4 v0 = *(const float4*)(x0 + off);
                float4 v1 = *(const float4*)(x1 + off);
                tX[row][(c4 << 2) + 0] = v0.x; tX[row][(c4 << 2) + 1] = v0.y;
                tX[row][(c4 << 2) + 2] = v0.z; tX[row][(c4 << 2) + 3] = v0.w;
                tY[row][(c4 << 2) + 0] = v1.x; tY[row][(c4 << 2) + 1] = v1.y;
                tY[row][(c4 << 2) + 2] = v1.z; tY[row][(c4 << 2) + 3] = v1.w;
            }
        }
        __syncthreads();
        {
            const int nc = tid & 63, dr4 = tid >> 6;
#pragma unroll
            for (int it = 0; it < 16; ++it) {
                int dr = dr4 + (it << 2);
                xT[(((size_t)(pb * NCH + d0 + dr)) << 12) + n0 + nc] =
                    make_float2(tX[nc][dr], tY[nc][dr]);
            }
        }
    } else {
        const int bid = blockIdx.x - 1024; // [nt:128][dpt:4]
        const int nt = bid >> 2, dpt = bid & 3;
        const int n0 = nt << 6, dp0 = dpt << 6;
        {
            const int c = tid & 63, r4 = tid >> 6;
#pragma unroll
            for (int it = 0; it < 16; ++it) {
                int row = r4 + (it << 2);
                int nn = n0 + row;
                float2 v = make_float2(0.f, 0.f);
                if (nn < TLEN)
                    v = *(const float2*)(t + (size_t)nn * NCH + ((dp0 + c) << 1));
                tX[row][c] = v.x;
                tY[row][c] = v.y;
            }
        }
        __syncthreads();
        {
            const int nc = tid & 63, dr4 = tid >> 6;
#pragma unroll
            for (int it = 0; it < 16; ++it) {
                int dr = dr4 + (it << 2);
                tT[(((size_t)(dp0 + dr)) << 13) + n0 + nc] =
                    make_float2(tX[nc][dr], tY[nc][dr]);
            }
        }
    }
}

// ---------------------------------------------------------------- t spectra --
// Monolithic 8192 FFT (32x32x8), channels d0=2*bid, d1=2*bid+1 packed, input
// from tT (coalesced). Emits parity-split spectrum in WAVE-CONTIGUOUS chunk
// layout: f2 position p = (q<<9) + 2*t + e holds bin for conv-thread t's
// a[j], j = 2q+e: kp = (t>>4) + ((t&15)<<4) + (BREV4[j]<<8). Prescaled 1/8192.
__global__ __launch_bounds__(256) void tfft3_kernel(const float2* __restrict__ tT,
                                                    const float2* __restrict__ tw,
                                                    float2* __restrict__ Tc) {
    __shared__ float2 z[N_FFT];
    const int tid = threadIdx.x;
    const int d0 = blockIdx.x * 2;
    const int d1 = d0 + 1;
    const float2* tp = tT + ((size_t)blockIdx.x << 13);

    float2 a[32];
#pragma unroll
    for (int n1 = 0; n1 < 32; ++n1)
        a[n1] = tp[(n1 << 8) + tid];
    fft32_dif(a);
    {   // twiddle w^k1, w = tw[tid]; even/odd incremental chains
        float2 w = tw[tid], w2 = cmul(w, w);
        float2 we = make_float2(1.f, 0.f), wo = w;
#pragma unroll
        for (int k1 = 0; k1 < 32; k1 += 2) {
            z[SLOT(k1, tid)]     = (k1 == 0) ? a[0] : cmul(a[BREV5[k1]], we);
            z[SLOT(k1 + 1, tid)] = cmul(a[BREV5[k1 + 1]], wo);
            we = cmul(we, w2); wo = cmul(wo, w2);
        }
    }
    __syncthreads();

    {   // step B
        const int r = tid >> 3, n2p = tid & 7;
#pragma unroll
        for (int n1p = 0; n1p < 32; ++n1p)
            a[n1p] = z[SLOT(r, (n1p << 3) + n2p)];
        fft32_dif(a);
        float2 wb = tw[n2p << 5], wb2 = cmul(wb, wb);
        float2 be = make_float2(1.f, 0.f), bo = wb;
#pragma unroll
        for (int k1p = 0; k1p < 32; k1p += 2) {
            z[SLOT(r, (k1p << 3) + n2p)]       = (k1p == 0) ? a[0] : cmul(a[BREV5[k1p]], be);
            z[SLOT(r, ((k1p + 1) << 3) + n2p)] = cmul(a[BREV5[k1p + 1]], bo);
            be = cmul(be, wb2); bo = cmul(bo, wb2);
        }
    }
    __syncthreads();

    // step C: 8-point FFTs
#pragma unroll
    for (int u = 0; u < 4; ++u) {
        int f = tid + (u << 8);
        int k1 = f >> 5, k1p = f & 31;
        float2 b[8];
#pragma unroll
        for (int e = 0; e < 8; ++e) b[e] = z[SLOT(k1, (k1p << 3) + e)];
        fft8_dif(b);
#pragma unroll
        for (int j = 0; j < 8; ++j) z[SLOT(k1, (k1p << 3) + j)] = b[j];
    }
    __syncthreads();

    // Hermitian unpack, iterated output-position-major (coalesced writes)
    const float sc = 0.5f / (float)N_FFT;   // fold in ifft 1/N
#pragma unroll
    for (int v = 0; v < 16; ++v) {
        int p = tid + (v << 8);                 // f2 position in [0,4096)
        int q   = p >> 9;
        int rem = p & 511;
        int t_  = rem >> 1, e = rem & 1;
        int j_  = (q << 1) + e;
        int kp  = (t_ >> 4) + ((t_ & 15) << 4) + (BREV4[j_] << 8);
#pragma unroll
        for (int par = 0; par < 2; ++par) {
            int k  = 2 * kp + par;
            int km = (N_FFT - k) & (N_FFT - 1);
            float2 A = z[ZADDR(k)];
            float2 B = z[ZADDR(km)];
            float2 Bj = make_float2(B.x, -B.y);
            float2 T0 = make_float2((A.x + Bj.x) * sc, (A.y + Bj.y) * sc);
            float2 dd = csub(A, Bj);
            float2 T1 = make_float2(dd.y * sc, -dd.x * sc);
            Tc[(size_t)d0 * N_FFT + (par << 12) + p] = T0;
            Tc[(size_t)d1 * N_FFT + (par << 12) + p] = T1;
        }
    }
}

// ---------------------------------------------------------------- main conv --
// conv6: grid 1024, one (d, pb) per 256-thread block, 32 KB LDS -> 4 blocks/CU
// (desynced phases fill each other's barrier stalls). Parity chains run
// sequentially in the single plane; even-chain result held as ie[0..7] in regs
// + U_e[8..15] parked in block-private scratch (dead tT buffer). Only 2
// barriers per chain: A->B and Binv->Ainv (B<->C are same-wave; chain->chain
// A-writes/Ainv-reads are column-private per thread).
__global__ __launch_bounds__(256, 4) void conv6_kernel(float2* __restrict__ xoT,
                                                       const float2* __restrict__ tw,
                                                       const float2* __restrict__ Tc,
                                                       float2* __restrict__ scrbuf) {
    __shared__ float2 z[SEQ];          // 32 KB: 16 rows x 256 cols
    const int t = threadIdx.x;
    // XCD swizzle; pb-pair of each d lands in the same chunk (Tc L2 reuse)
    const int sb = (blockIdx.x & 7) * 128 + (blockIdx.x >> 3);
    const int d  = sb >> 1;
    const int pb = sb & 1;
    float2* xp  = xoT + ((size_t)(pb * NCH + d) << 12);
    float2* scr = scrbuf + ((size_t)sb << 11);      // 2048 f2 = 16 KB private

    float2 a[16], ie[8];

#pragma unroll
    for (int par = 0; par < 2; ++par) {
        // ---- stage A: load row (+modulate for odd chain), fft16, twiddle
        if (par == 0) {
#pragma unroll
            for (int n1 = 0; n1 < 16; ++n1)
                a[n1] = xp[(n1 << 8) + t];
        } else {
#pragma unroll
            for (int n1 = 0; n1 < 16; ++n1)
                a[n1] = cmul(xp[(n1 << 8) + t], tw[(n1 << 8) + t]);
        }
        fft16_dif(a);
        {
            float2 w = tw[2 * t];        // W_4096^t
            float2 w2 = cmul(w, w);
            float2 we = make_float2(1.f, 0.f), wo = w;
#pragma unroll
            for (int k1 = 0; k1 < 16; k1 += 2) {
                z[SLOT16(k1, t)]     = (k1 == 0) ? a[0] : cmul(a[BREV4[k1]], we);
                z[SLOT16(k1 + 1, t)] = cmul(a[BREV4[k1 + 1]], wo);
                we = cmul(we, w2); wo = cmul(wo, w2);
            }
        }
        __syncthreads();                 // A writes read cross-thread by B

        // ---- stage B: FFT16 over n2 for (k1, n3)
        {
            const int k1 = t >> 4, n3 = t & 15;
#pragma unroll
            for (int n2 = 0; n2 < 16; ++n2)
                a[n2] = z[SLOT16(k1, (n2 << 4) + n3)];
            fft16_dif(a);
            float2 wb = tw[n3 << 5];     // W_256^{n3}
            float2 wb2 = cmul(wb, wb);
            float2 be = make_float2(1.f, 0.f), bo = wb;
#pragma unroll
            for (int r1 = 0; r1 < 16; r1 += 2) {
                z[SLOT16(k1, (r1 << 4) + n3)]       = (r1 == 0) ? a[0] : cmul(a[BREV4[r1]], be);
                z[SLOT16(k1, ((r1 + 1) << 4) + n3)] = cmul(a[BREV4[r1 + 1]], bo);
                be = cmul(be, wb2); bo = cmul(bo, wb2);
            }
        }
        // B->C exchange stays inside tids [16*k1, 16*k1+15] (one wave)
        __builtin_amdgcn_sched_barrier(0);

        // ---- stage C fwd + pointwise + stage C inverse
        {
            const int k1 = t >> 4, r1 = t & 15;
#pragma unroll
            for (int n3 = 0; n3 < 16; ++n3)
                a[n3] = z[SLOT16(k1, (r1 << 4) + n3)];
            fft16_dif(a);
            const float4* tp = (const float4*)(Tc + ((size_t)d << 13) + (par << 12));
#pragma unroll
            for (int q = 0; q < 8; ++q) {
                float4 f4 = tp[(q << 8) + t];       // 16B/lane contiguous
                a[2 * q]     = cmul(a[2 * q],     make_float2(f4.x, f4.y));
                a[2 * q + 1] = cmul(a[2 * q + 1], make_float2(f4.z, f4.w));
            }
            ifft16_dit(a);               // DIF output order == DIT input order
#pragma unroll
            for (int n3 = 0; n3 < 16; ++n3)
                z[SLOT16(k1, (r1 << 4) + n3)] = a[n3];
        }
        __builtin_amdgcn_sched_barrier(0);   // C->Binv: same 16-lane group

        // ---- stage B inverse
        {
            const int k1 = t >> 4, n3 = t & 15;
            float2 wb = tw[n3 << 5], wb2 = cmul(wb, wb);
            float2 be = make_float2(1.f, 0.f), bo = wb;
#pragma unroll
            for (int r1 = 0; r1 < 16; r1 += 2) {
                float2 v0 = z[SLOT16(k1, (r1 << 4) + n3)];
                float2 v1 = z[SLOT16(k1, ((r1 + 1) << 4) + n3)];
                a[BREV4[r1]]     = (r1 == 0) ? v0 : cmulj(v0, be);
                a[BREV4[r1 + 1]] = cmulj(v1, bo);
                be = cmul(be, wb2); bo = cmul(bo, wb2);
            }
            ifft16_dit(a);
#pragma unroll
            for (int n2 = 0; n2 < 16; ++n2)
                z[SLOT16(k1, (n2 << 4) + n3)] = a[n2];
        }
        __syncthreads();                 // Binv writes read cross-thread by Ainv

        // ---- stage A inverse (thread-private column slots)
        {
            float2 w = tw[2 * t], w2 = cmul(w, w);
            float2 we = make_float2(1.f, 0.f), wo = w;
#pragma unroll
            for (int k1 = 0; k1 < 16; k1 += 2) {
                float2 v0 = z[SLOT16(k1, t)];
                float2 v1 = z[SLOT16(k1 + 1, t)];
                a[BREV4[k1]]     = (k1 == 0) ? v0 : cmulj(v0, we);
                a[BREV4[k1 + 1]] = cmulj(v1, wo);
                we = cmul(we, w2); wo = cmul(wo, w2);
            }
            ifft16_dit(a);               // a[n1] = U_par[n1*256 + t]
        }
        // no barrier: next chain's A-writes are column-private vs Ainv reads

        if (par == 0) {
#pragma unroll
            for (int n1 = 0; n1 < 8; ++n1) ie[n1] = a[n1];
#pragma unroll
            for (int n1 = 8; n1 < 16; ++n1)
                scr[((n1 - 8) << 8) + t] = a[n1];            // coalesced 16 KB
        } else {
            // combine o[n] = U_e[n] + conj(w[n]) * U_o[n]
#pragma unroll
            for (int n1 = 0; n1 < 8; ++n1) {
                int n = (n1 << 8) + t;
                xp[n] = cadd(ie[n1], cmulj(a[n1], tw[n]));
            }
#pragma unroll
            for (int n1 = 8; n1 < 16; ++n1) {
                int n = (n1 << 8) + t;
                float2 ue = scr[((n1 - 8) << 8) + t];        // L2-hot readback
                xp[n] = cadd(ue, cmulj(a[n1], tw[n]));
            }
        }
    }
}

// ---------------------------------------------------------------- transpose --
// oT[pb][d][n] (float2: {b=2pb, b=2pb+1}) -> out[b][n][d]. LDS-tiled 32d x 64n.
__global__ __launch_bounds__(256) void transpose_out(const float2* __restrict__ oT,
                                                     float* __restrict__ out) {
    __shared__ float2 tile[32][65];
    const int tid = threadIdx.x;
    const int bid = blockIdx.x;
    const int pb = bid >> 10;
    const int dt = (bid >> 6) & 15;
    const int nt = bid & 63;
    const int d0 = dt << 5, n0 = nt << 6;

    {
        const int nl = tid & 63, dl = tid >> 6;
#pragma unroll
        for (int i = 0; i < 8; ++i) {
            int dd = dl + (i << 2);
            tile[dd][nl] = oT[(((size_t)(pb * NCH + d0 + dd)) << 12) + n0 + nl];
        }
    }
    __syncthreads();
    {
        const int dl = tid & 31, ns = tid >> 5;
        float* o0 = out + (size_t)(2 * pb) * SEQ * NCH;
        float* o1 = o0 + (size_t)SEQ * NCH;
#pragma unroll
        for (int j = 0; j < 8; ++j) {
            int nn = n0 + ns + (j << 3);
            float2 v = tile[dl][ns + (j << 3)];
            o0[(size_t)nn * NCH + d0 + dl] = v.x;
            o1[(size_t)nn * NCH + d0 + dl] = v.y;
        }
    }
}

// =================== fallback path (small ws) ===============================
__global__ __launch_bounds__(256) void tfft2_kernel(const float* __restrict__ t,
                                                    const float2* __restrict__ tw,
                                                    float2* __restrict__ Tc) {
    __shared__ float2 z[N_FFT];
    const int tid = threadIdx.x;
    const int d0 = blockIdx.x * 2;
    const int d1 = d0 + 1;

    float2 a[32];
#pragma unroll
    for (int n1 = 0; n1 < 32; ++n1) {
        int n = (n1 << 8) + tid;
        float va = 0.f, vb = 0.f;
        if (n < TLEN) {
            va = t[(size_t)n * NCH + d0];
            vb = t[(size_t)n * NCH + d1];
        }
        a[n1] = make_float2(va, vb);
    }
    fft32_dif(a);
    {
        float2 w = tw[tid], w2 = cmul(w, w);
        float2 we = make_float2(1.f, 0.f), wo = w;
#pragma unroll
        for (int k1 = 0; k1 < 32; k1 += 2) {
            z[SLOT(k1, tid)]     = (k1 == 0) ? a[0] : cmul(a[BREV5[k1]], we);
            z[SLOT(k1 + 1, tid)] = cmul(a[BREV5[k1 + 1]], wo);
            we = cmul(we, w2); wo = cmul(wo, w2);
        }
    }
    __syncthreads();
    {
        const int r = tid >> 3, n2p = tid & 7;
#pragma unroll
        for (int n1p = 0; n1p < 32; ++n1p)
            a[n1p] = z[SLOT(r, (n1p << 3) + n2p)];
        fft32_dif(a);
        float2 wb = tw[n2p << 5], wb2 = cmul(wb, wb);
        float2 be = make_float2(1.f, 0.f), bo = wb;
#pragma unroll
        for (int k1p = 0; k1p < 32; k1p += 2) {
            z[SLOT(r, (k1p << 3) + n2p)]       = (k1p == 0) ? a[0] : cmul(a[BREV5[k1p]], be);
            z[SLOT(r, ((k1p + 1) << 3) + n2p)] = cmul(a[BREV5[k1p + 1]], bo);
            be = cmul(be, wb2); bo = cmul(bo, wb2);
        }
    }
    __syncthreads();
#pragma unroll
    for (int u = 0; u < 4; ++u) {
        int f = tid + (u << 8);
        int k1 = f >> 5, k1p = f & 31;
        float2 b[8];
#pragma unroll
        for (int e = 0; e < 8; ++e) b[e] = z[SLOT(k1, (k1p << 3) + e)];
        fft8_dif(b);
#pragma unroll
        for (int j = 0; j < 8; ++j) z[SLOT(k1, (k1p << 3) + j)] = b[j];
    }
    __syncthreads();

    const float sc = 0.5f / (float)N_FFT;
#pragma unroll
    for (int v = 0; v < 16; ++v) {
        int s = tid + (v << 8);
        int k1 = s >> 8, r1 = (s >> 4) & 15, j = s & 15;
        int kp = k1 + (r1 << 4) + (BREV4[j] << 8);
#pragma unroll
        for (int par = 0; par < 2; ++par) {
            int k  = 2 * kp + par;
            int km = (N_FFT - k) & (N_FFT - 1);
            float2 A = z[ZADDR(k)];
            float2 B = z[ZADDR(km)];
            float2 Bj = make_float2(B.x, -B.y);
            float2 T0 = make_float2((A.x + Bj.x) * sc, (A.y + Bj.y) * sc);
            float2 dd = csub(A, Bj);
            float2 T1 = make_float2(dd.y * sc, -dd.x * sc);
            Tc[(size_t)d0 * N_FFT + (par << 12) + s] = T0;
            Tc[(size_t)d1 * N_FFT + (par << 12) + s] = T1;
        }
    }
}

template<bool OT>
__global__ __launch_bounds__(256, 2) void conv3_kernel(const float* __restrict__ x,
                                                       const float2* __restrict__ tw,
                                                       const float2* __restrict__ Tc,
                                                       float2* __restrict__ oT,
                                                       float* __restrict__ out) {
    __shared__ float2 z[SEQ];
    const int tid = threadIdx.x;
    const int sb = (blockIdx.x & 7) * 128 + (blockIdx.x >> 3);
    const int d  = sb >> 1;
    const int pb = sb & 1;

    const float* x0 = x + (size_t)(2 * pb) * SEQ * NCH + d;
    const float* x1 = x0 + (size_t)SEQ * NCH;

    float2 a[16], ie[16];

#pragma unroll
    for (int par = 0; par < 2; ++par) {
        if (par == 1) __syncthreads();

        if (par == 0) {
#pragma unroll
            for (int n1 = 0; n1 < 16; ++n1) {
                int n = (n1 << 8) + tid;
                a[n1] = make_float2(x0[(size_t)n * NCH], x1[(size_t)n * NCH]);
            }
        } else {
#pragma unroll
            for (int n1 = 0; n1 < 16; ++n1) {
                int n = (n1 << 8) + tid;
                float2 v = make_float2(x0[(size_t)n * NCH], x1[(size_t)n * NCH]);
                a[n1] = cmul(v, tw[n]);
            }
        }
        fft16_dif(a);
        {
            float2 w = tw[2 * tid], w2 = cmul(w, w);
            float2 we = make_float2(1.f, 0.f), wo = w;
#pragma unroll
            for (int k1 = 0; k1 < 16; k1 += 2) {
                z[SLOT16(k1, tid)]     = (k1 == 0) ? a[0] : cmul(a[BREV4[k1]], we);
                z[SLOT16(k1 + 1, tid)] = cmul(a[BREV4[k1 + 1]], wo);
                we = cmul(we, w2); wo = cmul(wo, w2);
            }
        }
        __syncthreads();
        {
            const int k1 = tid >> 4, n3 = tid & 15;
#pragma unroll
            for (int n2 = 0; n2 < 16; ++n2)
                a[n2] = z[SLOT16(k1, (n2 << 4) + n3)];
            fft16_dif(a);
            float2 wb = tw[n3 << 5], wb2 = cmul(wb, wb);
            float2 be = make_float2(1.f, 0.f), bo = wb;
#pragma unroll
            for (int r1 = 0; r1 < 16; r1 += 2) {
                z[SLOT16(k1, (r1 << 4) + n3)]       = (r1 == 0) ? a[0] : cmul(a[BREV4[r1]], be);
                z[SLOT16(k1, ((r1 + 1) << 4) + n3)] = cmul(a[BREV4[r1 + 1]], bo);
                be = cmul(be, wb2); bo = cmul(bo, wb2);
            }
        }
        __syncthreads();
        {
            const int k1 = tid >> 4, r1 = tid & 15;
#pragma unroll
            for (int n3 = 0; n3 < 16; ++n3)
                a[n3] = z[SLOT16(k1, (r1 << 4) + n3)];
            fft16_dif(a);
            const float2* Td = Tc + ((size_t)d << 13) + (par << 12);
#pragma unroll
            for (int j = 0; j < 16; ++j) {
                // matches tfft2 layout: s = (k1<<8)+(r1<<4)+j
                float2 T = Td[((tid >> 4) << 8) + ((tid & 15) << 4) + j];
                a[j] = cmul(a[j], T);
            }
            ifft16_dit(a);
#pragma unroll
            for (int n3 = 0; n3 < 16; ++n3)
                z[SLOT16(k1, (r1 << 4) + n3)] = a[n3];
        }
        __syncthreads();
        {
            const int k1 = tid >> 4, n3 = tid & 15;
            float2 wb = tw[n3 << 5], wb2 = cmul(wb, wb);
            float2 be = make_float2(1.f, 0.f), bo = wb;
#pragma unroll
            for (int r1 = 0; r1 < 16; r1 += 2) {
                float2 v0 = z[SLOT16(k1, (r1 << 4) + n3)];
                float2 v1 = z[SLOT16(k1, ((r1 + 1) << 4) + n3)];
                a[BREV4[r1]]     = (r1 == 0) ? v0 : cmulj(v0, be);
                a[BREV4[r1 + 1]] = cmulj(v1, bo);
                be = cmul(be, wb2); bo = cmul(bo, wb2);
            }
            ifft16_dit(a);
#pragma unroll
            for (int n2 = 0; n2 < 16; ++n2)
                z[SLOT16(k1, (n2 << 4) + n3)] = a[n2];
        }
        __syncthreads();
        {
            float2 w = tw[2 * tid], w2 = cmul(w, w);
            float2 we = make_float2(1.f, 0.f), wo = w;
#pragma unroll
            for (int k1 = 0; k1 < 16; k1 += 2) {
                float2 v0 = z[SLOT16(k1, tid)];
                float2 v1 = z[SLOT16(k1 + 1, tid)];
                a[BREV4[k1]]     = (k1 == 0) ? v0 : cmulj(v0, we);
                a[BREV4[k1 + 1]] = cmulj(v1, wo);
                we = cmul(we, w2); wo = cmul(wo, w2);
            }
            ifft16_dit(a);
        }

        if (par == 0) {
#pragma unroll
            for (int n1 = 0; n1 < 16; ++n1) ie[n1] = a[n1];
        } else {
            if constexpr (OT) {
                float2* op = oT + (((size_t)(pb * NCH + d)) << 12);
#pragma unroll
                for (int n1 = 0; n1 < 16; ++n1) {
                    int n = (n1 << 8) + tid;
                    op[n] = cadd(ie[n1], cmulj(a[n1], tw[n]));
                }
            } else {
                float* o0 = out + (size_t)(2 * pb) * SEQ * NCH + d;
                float* o1 = o0 + (size_t)SEQ * NCH;
#pragma unroll
                for (int n1 = 0; n1 < 16; ++n1) {
                    int n = (n1 << 8) + tid;
                    float2 o = cadd(ie[n1], cmulj(a[n1], tw[n]));
                    o0[(size_t)n * NCH] = o.x;
                    o1[(size_t)n * NCH] = o.y;
                }
            }
        }
    }
}

extern "C" void kernel_launch(void* const* d_in, const int* in_sizes, int n_in,
                              void* d_out, int out_size, void* d_ws, size_t ws_size,
                              hipStream_t stream) {
    (void)in_sizes; (void)n_in; (void)out_size;
    const float* x = (const float*)d_in[0];
    const float* t = (const float*)d_in[1];
    float* out = (float*)d_out;

    float2* tw  = (float2*)d_ws;                   // 8192 f2 = 64 KB
    float2* Tc  = tw + N_FFT;                      // 512*8192 f2 = 33.55 MB
    float2* xoT = Tc + (size_t)NCH * N_FFT;        // 2*512*4096 f2 = 33.55 MB
    float2* tT  = xoT + 2ull * NCH * SEQ;          // 256*8192 f2 = 16.78 MB
                                                   // (reused as conv6 scratch)

    const size_t need_full = sizeof(float2) * ((size_t)N_FFT + (size_t)NCH * N_FFT
                                               + 2ull * NCH * SEQ
                                               + 256ull * N_FFT);   // ~84 MB
    const size_t need_ot   = sizeof(float2) * ((size_t)N_FFT + (size_t)NCH * N_FFT
                                               + 2ull * NCH * SEQ); // ~67.2 MB

    twiddle_init<<<N_FFT / 256, 256, 0, stream>>>(tw);
    if (ws_size >= need_full) {
        transpose_in<<<1536, 256, 0, stream>>>(x, t, xoT, tT);
        tfft3_kernel<<<NCH / 2, 256, 0, stream>>>(tT, tw, Tc);
        conv6_kernel<<<1024, 256, 0, stream>>>(xoT, tw, Tc, tT);
        transpose_out<<<2048, 256, 0, stream>>>(xoT, out);
    } else if (ws_size >= need_ot) {
        tfft2_kernel<<<NCH / 2, 256, 0, stream>>>(t, tw, Tc);
        conv3_kernel<true><<<1024, 256, 0, stream>>>(x, tw, Tc, xoT, out);
        transpose_out<<<2048, 256, 0, stream>>>(xoT, out);
    } else {
        tfft2_kernel<<<NCH / 2, 256, 0, stream>>>(t, tw, Tc);
        conv3_kernel<false><<<1024, 256, 0, stream>>>(x, tw, Tc, nullptr, out);
    }
}

// Round 12
// 92.850 us; speedup vs baseline: 1.2248x; 1.2248x over previous
//
#include <hip/hip_runtime.h>
#include <math.h>

// Problem constants (b=4, n=m=l=4096, d=512, fft_len=8192, t_len=2l-2=8190)
#define N_FFT   8192
#define SEQ     4096
#define NCH     512
#define TLEN    8190

__device__ __forceinline__ float2 cmul(float2 a, float2 b) {
    return make_float2(a.x * b.x - a.y * b.y, a.x * b.y + a.y * b.x);
}
__device__ __forceinline__ float2 cmulj(float2 a, float2 b) {   // a * conj(b)
    return make_float2(a.x * b.x + a.y * b.y, a.y * b.x - a.x * b.y);
}
__device__ __forceinline__ float2 cadd(float2 a, float2 b) {
    return make_float2(a.x + b.x, a.y + b.y);
}
__device__ __forceinline__ float2 csub(float2 a, float2 b) {
    return make_float2(a.x - b.x, a.y - b.y);
}

// W32^j = exp(-2*pi*i*j/32), j in [0,16)
constexpr float W32C[16] = {
    1.0f, 0.9807852804032304f, 0.9238795325112867f, 0.8314696123025452f,
    0.7071067811865476f, 0.5555702330196023f, 0.3826834323650898f, 0.1950903220161283f,
    0.0f, -0.1950903220161282f, -0.3826834323650897f, -0.5555702330196020f,
    -0.7071067811865475f, -0.8314696123025453f, -0.9238795325112867f, -0.9807852804032304f
};
constexpr float W32S[16] = {
    -0.0f, -0.1950903220161283f, -0.3826834323650898f, -0.5555702330196022f,
    -0.7071067811865476f, -0.8314696123025452f, -0.9238795325112867f, -0.9807852804032304f,
    -1.0f, -0.9807852804032304f, -0.9238795325112867f, -0.8314696123025453f,
    -0.7071067811865476f, -0.5555702330196022f, -0.3826834323650899f, -0.1950903220161286f
};

constexpr int BREV5[32] = {0,16,8,24,4,20,12,28,2,18,10,26,6,22,14,30,
                           1,17,9,25,5,21,13,29,3,19,11,27,7,23,15,31};
constexpr int BREV4[16] = {0,8,4,12,2,10,6,14,1,9,5,13,3,11,7,15};

__device__ __forceinline__ int brev3i(int b) {
    return ((b & 1) << 2) | (b & 2) | ((b & 4) >> 2);
}

// ---------------------------------------------------------------- reg FFTs ---
__device__ __forceinline__ void fft32_dif(float2 a[32]) {
#pragma unroll
    for (int s = 4; s >= 0; --s) {
        const int h = 1 << s;
#pragma unroll
        for (int g = 0; g < 32; g += 2 * h) {
#pragma unroll
            for (int i = 0; i < h; ++i) {
                float2 x0 = a[g + i], x1 = a[g + i + h];
                a[g + i] = cadd(x0, x1);
                float2 w = make_float2(W32C[i << (4 - s)], W32S[i << (4 - s)]);
                a[g + i + h] = cmul(csub(x0, x1), w);
            }
        }
    }
}

__device__ __forceinline__ void fft16_dif(float2 a[16]) {
#pragma unroll
    for (int s = 3; s >= 0; --s) {
        const int h = 1 << s;
#pragma unroll
        for (int g = 0; g < 16; g += 2 * h) {
#pragma unroll
            for (int i = 0; i < h; ++i) {
                float2 x0 = a[g + i], x1 = a[g + i + h];
                a[g + i] = cadd(x0, x1);
                float2 w = make_float2(W32C[i << (4 - s)], W32S[i << (4 - s)]);
                a[g + i + h] = cmul(csub(x0, x1), w);
            }
        }
    }
}

__device__ __forceinline__ void ifft16_dit(float2 a[16]) {
#pragma unroll
    for (int s = 0; s <= 3; ++s) {
        const int h = 1 << s;
#pragma unroll
        for (int g = 0; g < 16; g += 2 * h) {
#pragma unroll
            for (int i = 0; i < h; ++i) {
                float2 w = make_float2(W32C[i << (4 - s)], -W32S[i << (4 - s)]);
                float2 t = cmul(a[g + i + h], w);
                float2 x0 = a[g + i];
                a[g + i] = cadd(x0, t);
                a[g + i + h] = csub(x0, t);
            }
        }
    }
}

__device__ __forceinline__ void fft8_dif(float2 a[8]) {
#pragma unroll
    for (int s = 2; s >= 0; --s) {
        const int h = 1 << s;
#pragma unroll
        for (int g = 0; g < 8; g += 2 * h) {
#pragma unroll
            for (int i = 0; i < h; ++i) {
                float2 x0 = a[g + i], x1 = a[g + i + h];
                a[g + i] = cadd(x0, x1);
                int e = (i << (2 - s)) << 2;   // W8^m = W32^{4m}
                float2 w = make_float2(W32C[e], W32S[e]);
                a[g + i + h] = cmul(csub(x0, x1), w);
            }
        }
    }
}

// bank-conflict-reduced LDS slot, 32-row layout (tfft)
__device__ __forceinline__ int SLOT(int r, int c) {
    return (r << 8) + (c ^ ((c >> 4) & 7) ^ ((r & 1) << 3));
}
// LDS slot of frequency bin q after tfft forward stage C
__device__ __forceinline__ int ZADDR(int q) {
    return SLOT(q & 31, (((q >> 5) & 31) << 3) + brev3i((q >> 10) & 7));
}
// 16-row layout (conv)
__device__ __forceinline__ int SLOT16(int r, int c) {
    return (r << 8) + (c ^ ((c >> 4) & 7) ^ ((r & 1) << 3));
}

// ---------------------------------------------------------------- twiddles ---
__global__ __launch_bounds__(256) void twiddle_init(float2* __restrict__ tw) {
    int k = blockIdx.x * 256 + threadIdx.x;
    double th = -2.0 * 3.14159265358979323846 * (double)k / (double)N_FFT;
    tw[k] = make_float2((float)cos(th), (float)sin(th));
}

// ---------------------------------------------------------------- transposes -
// Fused input transposes.
// bid < 1024:  x[b][n][d] -> xT[pb][d][n]  (64n x 64d tiles, float4 loads)
// bid >= 1024: t[n][d] -> tT[dp][n] (zero-padded to 8192)
__global__ __launch_bounds__(256) void transpose_in(const float* __restrict__ x,
                                                    const float* __restrict__ t,
                                                    float2* __restrict__ xT,
                                                    float2* __restrict__ tT) {
    __shared__ float tX[64][65], tY[64][65];
    const int tid = threadIdx.x;
    if (blockIdx.x < 1024) {
        const int bid = blockIdx.x;        // [pb:2][dt:8][nt:64]
        const int pb = bid >> 9;
        const int dt = (bid >> 6) & 7;
        const int nt = bid & 63;
        const int d0 = dt << 6, n0 = nt << 6;
        const float* x0 = x + (size_t)(2 * pb) * SEQ * NCH;
        const float* x1 = x0 + (size_t)SEQ * NCH;
        {
            const int c4 = tid & 15, r16 = tid >> 4;   // 16 float4 cols, 16 rows
#pragma unroll
            for (int it = 0; it < 4; ++it) {
                int row = r16 + (it << 4);
                size_t off = (size_t)(n0 + row) * NCH + d0 + (c4 << 2);
                float4 v0 = *(const float4*)(x0 + off);
                float4 v1 = *(const float4*)(x1 + off);
                tX[row][(c4 << 2) + 0] = v0.x; tX[row][(c4 << 2) + 1] = v0.y;
                tX[row][(c4 << 2) + 2] = v0.z; tX[row][(c4 << 2) + 3] = v0.w;
                tY[row][(c4 << 2) + 0] = v1.x; tY[row][(c4 << 2) + 1] = v1.y;
                tY[row][(c4 << 2) + 2] = v1.z; tY[row][(c4 << 2) + 3] = v1.w;
            }
        }
        __syncthreads();
        {
            const int nc = tid & 63, dr4 = tid >> 6;
#pragma unroll
            for (int it = 0; it < 16; ++it) {
                int dr = dr4 + (it << 2);
                xT[(((size_t)(pb * NCH + d0 + dr)) << 12) + n0 + nc] =
                    make_float2(tX[nc][dr], tY[nc][dr]);
            }
        }
    } else {
        const int bid = blockIdx.x - 1024; // [nt:128][dpt:4]
        const int nt = bid >> 2, dpt = bid & 3;
        const int n0 = nt << 6, dp0 = dpt << 6;
        {
            const int c = tid & 63, r4 = tid >> 6;
#pragma unroll
            for (int it = 0; it < 16; ++it) {
                int row = r4 + (it << 2);
                int nn = n0 + row;
                float2 v = make_float2(0.f, 0.f);
                if (nn < TLEN)
                    v = *(const float2*)(t + (size_t)nn * NCH + ((dp0 + c) << 1));
                tX[row][c] = v.x;
                tY[row][c] = v.y;
            }
        }
        __syncthreads();
        {
            const int nc = tid & 63, dr4 = tid >> 6;
#pragma unroll
            for (int it = 0; it < 16; ++it) {
                int dr = dr4 + (it << 2);
                tT[(((size_t)(dp0 + dr)) << 13) + n0 + nc] =
                    make_float2(tX[nc][dr], tY[nc][dr]);
            }
        }
    }
}

// ---------------------------------------------------------------- t spectra --
// Monolithic 8192 FFT (32x32x8), channels d0=2*bid, d1=2*bid+1 packed, input
// from tT (coalesced). Emits parity-split spectrum in WAVE-CONTIGUOUS chunk
// layout: f2 position p = (q<<9) + 2*t + e holds bin for conv-thread t's
// a[j], j = 2q+e: kp = (t>>4) + ((t&15)<<4) + (BREV4[j]<<8). Prescaled 1/8192.
__global__ __launch_bounds__(256) void tfft3_kernel(const float2* __restrict__ tT,
                                                    const float2* __restrict__ tw,
                                                    float2* __restrict__ Tc) {
    __shared__ float2 z[N_FFT];
    const int tid = threadIdx.x;
    const int d0 = blockIdx.x * 2;
    const int d1 = d0 + 1;
    const float2* tp = tT + ((size_t)blockIdx.x << 13);

    float2 a[32];
#pragma unroll
    for (int n1 = 0; n1 < 32; ++n1)
        a[n1] = tp[(n1 << 8) + tid];
    fft32_dif(a);
    {   // twiddle w^k1, w = tw[tid]; even/odd incremental chains
        float2 w = tw[tid], w2 = cmul(w, w);
        float2 we = make_float2(1.f, 0.f), wo = w;
#pragma unroll
        for (int k1 = 0; k1 < 32; k1 += 2) {
            z[SLOT(k1, tid)]     = (k1 == 0) ? a[0] : cmul(a[BREV5[k1]], we);
            z[SLOT(k1 + 1, tid)] = cmul(a[BREV5[k1 + 1]], wo);
            we = cmul(we, w2); wo = cmul(wo, w2);
        }
    }
    __syncthreads();

    {   // step B
        const int r = tid >> 3, n2p = tid & 7;
#pragma unroll
        for (int n1p = 0; n1p < 32; ++n1p)
            a[n1p] = z[SLOT(r, (n1p << 3) + n2p)];
        fft32_dif(a);
        float2 wb = tw[n2p << 5], wb2 = cmul(wb, wb);
        float2 be = make_float2(1.f, 0.f), bo = wb;
#pragma unroll
        for (int k1p = 0; k1p < 32; k1p += 2) {
            z[SLOT(r, (k1p << 3) + n2p)]       = (k1p == 0) ? a[0] : cmul(a[BREV5[k1p]], be);
            z[SLOT(r, ((k1p + 1) << 3) + n2p)] = cmul(a[BREV5[k1p + 1]], bo);
            be = cmul(be, wb2); bo = cmul(bo, wb2);
        }
    }
    __syncthreads();

    // step C: 8-point FFTs
#pragma unroll
    for (int u = 0; u < 4; ++u) {
        int f = tid + (u << 8);
        int k1 = f >> 5, k1p = f & 31;
        float2 b[8];
#pragma unroll
        for (int e = 0; e < 8; ++e) b[e] = z[SLOT(k1, (k1p << 3) + e)];
        fft8_dif(b);
#pragma unroll
        for (int j = 0; j < 8; ++j) z[SLOT(k1, (k1p << 3) + j)] = b[j];
    }
    __syncthreads();

    // Hermitian unpack, iterated output-position-major (coalesced writes)
    const float sc = 0.5f / (float)N_FFT;   // fold in ifft 1/N
#pragma unroll
    for (int v = 0; v < 16; ++v) {
        int p = tid + (v << 8);                 // f2 position in [0,4096)
        int q   = p >> 9;
        int rem = p & 511;
        int t_  = rem >> 1, e = rem & 1;
        int j_  = (q << 1) + e;
        int kp  = (t_ >> 4) + ((t_ & 15) << 4) + (BREV4[j_] << 8);
#pragma unroll
        for (int par = 0; par < 2; ++par) {
            int k  = 2 * kp + par;
            int km = (N_FFT - k) & (N_FFT - 1);
            float2 A = z[ZADDR(k)];
            float2 B = z[ZADDR(km)];
            float2 Bj = make_float2(B.x, -B.y);
            float2 T0 = make_float2((A.x + Bj.x) * sc, (A.y + Bj.y) * sc);
            float2 dd = csub(A, Bj);
            float2 T1 = make_float2(dd.y * sc, -dd.x * sc);
            Tc[(size_t)d0 * N_FFT + (par << 12) + p] = T0;
            Tc[(size_t)d1 * N_FFT + (par << 12) + p] = T1;
        }
    }
}

// ---------------------------------------------------------------- main conv --
// conv6: grid 1024, one (d, pb) per 256-thread block, 40 KB LDS (32 KB work
// plane + 8 KB U_e side-buffer) -> 4 blocks/CU, desynced phases. Parity
// chains sequential; even-chain result: ie[0..11] in regs, U_e[12..15] in
// zx (same-thread write/read -> no barrier, no global scratch traffic).
// launch_bounds min-waves=2: allocator headroom (the =4 variants force a
// 64-VGPR target and spill to scratch -- R9/R11 regressions).
__global__ __launch_bounds__(256, 2) void conv6_kernel(float2* __restrict__ xoT,
                                                       const float2* __restrict__ tw,
                                                       const float2* __restrict__ Tc) {
    __shared__ float2 z[SEQ];          // 32 KB: 16 rows x 256 cols
    __shared__ float2 zx[1024];        // 8 KB: U_e[12..15] parking
    const int t = threadIdx.x;
    // XCD swizzle; pb-pair of each d lands in the same chunk (Tc L2 reuse)
    const int sb = (blockIdx.x & 7) * 128 + (blockIdx.x >> 3);
    const int d  = sb >> 1;
    const int pb = sb & 1;
    float2* xp  = xoT + ((size_t)(pb * NCH + d) << 12);

    float2 a[16], ie[12];

#pragma unroll
    for (int par = 0; par < 2; ++par) {
        // ---- stage A: load row (+modulate for odd chain), fft16, twiddle
        if (par == 0) {
#pragma unroll
            for (int n1 = 0; n1 < 16; ++n1)
                a[n1] = xp[(n1 << 8) + t];
        } else {
#pragma unroll
            for (int n1 = 0; n1 < 16; ++n1)
                a[n1] = cmul(xp[(n1 << 8) + t], tw[(n1 << 8) + t]);
        }
        fft16_dif(a);
        {
            float2 w = tw[2 * t];        // W_4096^t
            float2 w2 = cmul(w, w);
            float2 we = make_float2(1.f, 0.f), wo = w;
#pragma unroll
            for (int k1 = 0; k1 < 16; k1 += 2) {
                z[SLOT16(k1, t)]     = (k1 == 0) ? a[0] : cmul(a[BREV4[k1]], we);
                z[SLOT16(k1 + 1, t)] = cmul(a[BREV4[k1 + 1]], wo);
                we = cmul(we, w2); wo = cmul(wo, w2);
            }
        }
        __syncthreads();                 // A writes read cross-thread by B

        // ---- stage B: FFT16 over n2 for (k1, n3)
        {
            const int k1 = t >> 4, n3 = t & 15;
#pragma unroll
            for (int n2 = 0; n2 < 16; ++n2)
                a[n2] = z[SLOT16(k1, (n2 << 4) + n3)];
            fft16_dif(a);
            float2 wb = tw[n3 << 5];     // W_256^{n3}
            float2 wb2 = cmul(wb, wb);
            float2 be = make_float2(1.f, 0.f), bo = wb;
#pragma unroll
            for (int r1 = 0; r1 < 16; r1 += 2) {
                z[SLOT16(k1, (r1 << 4) + n3)]       = (r1 == 0) ? a[0] : cmul(a[BREV4[r1]], be);
                z[SLOT16(k1, ((r1 + 1) << 4) + n3)] = cmul(a[BREV4[r1 + 1]], bo);
                be = cmul(be, wb2); bo = cmul(bo, wb2);
            }
        }
        // B->C exchange stays inside tids [16*k1, 16*k1+15] (one wave)
        __builtin_amdgcn_sched_barrier(0);

        // ---- stage C fwd + pointwise + stage C inverse
        {
            const int k1 = t >> 4, r1 = t & 15;
#pragma unroll
            for (int n3 = 0; n3 < 16; ++n3)
                a[n3] = z[SLOT16(k1, (r1 << 4) + n3)];
            fft16_dif(a);
            const float4* tp = (const float4*)(Tc + ((size_t)d << 13) + (par << 12));
#pragma unroll
            for (int q = 0; q < 8; ++q) {
                float4 f4 = tp[(q << 8) + t];       // 16B/lane contiguous
                a[2 * q]     = cmul(a[2 * q],     make_float2(f4.x, f4.y));
                a[2 * q + 1] = cmul(a[2 * q + 1], make_float2(f4.z, f4.w));
            }
            ifft16_dit(a);               // DIF output order == DIT input order
#pragma unroll
            for (int n3 = 0; n3 < 16; ++n3)
                z[SLOT16(k1, (r1 << 4) + n3)] = a[n3];
        }
        __builtin_amdgcn_sched_barrier(0);   // C->Binv: same 16-lane group

        // ---- stage B inverse
        {
            const int k1 = t >> 4, n3 = t & 15;
            float2 wb = tw[n3 << 5], wb2 = cmul(wb, wb);
            float2 be = make_float2(1.f, 0.f), bo = wb;
#pragma unroll
            for (int r1 = 0; r1 < 16; r1 += 2) {
                float2 v0 = z[SLOT16(k1, (r1 << 4) + n3)];
                float2 v1 = z[SLOT16(k1, ((r1 + 1) << 4) + n3)];
                a[BREV4[r1]]     = (r1 == 0) ? v0 : cmulj(v0, be);
                a[BREV4[r1 + 1]] = cmulj(v1, bo);
                be = cmul(be, wb2); bo = cmul(bo, wb2);
            }
            ifft16_dit(a);
#pragma unroll
            for (int n2 = 0; n2 < 16; ++n2)
                z[SLOT16(k1, (n2 << 4) + n3)] = a[n2];
        }
        __syncthreads();                 // Binv writes read cross-thread by Ainv

        // ---- stage A inverse (thread-private column slots)
        {
            float2 w = tw[2 * t], w2 = cmul(w, w);
            float2 we = make_float2(1.f, 0.f), wo = w;
#pragma unroll
            for (int k1 = 0; k1 < 16; k1 += 2) {
                float2 v0 = z[SLOT16(k1, t)];
                float2 v1 = z[SLOT16(k1 + 1, t)];
                a[BREV4[k1]]     = (k1 == 0) ? v0 : cmulj(v0, we);
                a[BREV4[k1 + 1]] = cmulj(v1, wo);
                we = cmul(we, w2); wo = cmul(wo, w2);
            }
            ifft16_dit(a);               // a[n1] = U_par[n1*256 + t]
        }
        // no barrier: next chain's A-writes are column-private vs Ainv reads;
        // zx write/read is same-thread.

        if (par == 0) {
#pragma unroll
            for (int n1 = 0; n1 < 12; ++n1) ie[n1] = a[n1];
#pragma unroll
            for (int n1 = 12; n1 < 16; ++n1)
                zx[((n1 - 12) << 8) + t] = a[n1];
        } else {
            // combine o[n] = U_e[n] + conj(w[n]) * U_o[n]
#pragma unroll
            for (int n1 = 0; n1 < 12; ++n1) {
                int n = (n1 << 8) + t;
                xp[n] = cadd(ie[n1], cmulj(a[n1], tw[n]));
            }
#pragma unroll
            for (int n1 = 12; n1 < 16; ++n1) {
                int n = (n1 << 8) + t;
                float2 ue = zx[((n1 - 12) << 8) + t];
                xp[n] = cadd(ue, cmulj(a[n1], tw[n]));
            }
        }
    }
}

// ---------------------------------------------------------------- transpose --
// oT[pb][d][n] (float2: {b=2pb, b=2pb+1}) -> out[b][n][d]. LDS-tiled 32d x 64n.
__global__ __launch_bounds__(256) void transpose_out(const float2* __restrict__ oT,
                                                     float* __restrict__ out) {
    __shared__ float2 tile[32][65];
    const int tid = threadIdx.x;
    const int bid = blockIdx.x;
    const int pb = bid >> 10;
    const int dt = (bid >> 6) & 15;
    const int nt = bid & 63;
    const int d0 = dt << 5, n0 = nt << 6;

    {
        const int nl = tid & 63, dl = tid >> 6;
#pragma unroll
        for (int i = 0; i < 8; ++i) {
            int dd = dl + (i << 2);
            tile[dd][nl] = oT[(((size_t)(pb * NCH + d0 + dd)) << 12) + n0 + nl];
        }
    }
    __syncthreads();
    {
        const int dl = tid & 31, ns = tid >> 5;
        float* o0 = out + (size_t)(2 * pb) * SEQ * NCH;
        float* o1 = o0 + (size_t)SEQ * NCH;
#pragma unroll
        for (int j = 0; j < 8; ++j) {
            int nn = n0 + ns + (j << 3);
            float2 v = tile[dl][ns + (j << 3)];
            o0[(size_t)nn * NCH + d0 + dl] = v.x;
            o1[(size_t)nn * NCH + d0 + dl] = v.y;
        }
    }
}

// =================== fallback path (small ws) ===============================
__global__ __launch_bounds__(256) void tfft2_kernel(const float* __restrict__ t,
                                                    const float2* __restrict__ tw,
                                                    float2* __restrict__ Tc) {
    __shared__ float2 z[N_FFT];
    const int tid = threadIdx.x;
    const int d0 = blockIdx.x * 2;
    const int d1 = d0 + 1;

    float2 a[32];
#pragma unroll
    for (int n1 = 0; n1 < 32; ++n1) {
        int n = (n1 << 8) + tid;
        float va = 0.f, vb = 0.f;
        if (n < TLEN) {
            va = t[(size_t)n * NCH + d0];
            vb = t[(size_t)n * NCH + d1];
        }
        a[n1] = make_float2(va, vb);
    }
    fft32_dif(a);
    {
        float2 w = tw[tid], w2 = cmul(w, w);
        float2 we = make_float2(1.f, 0.f), wo = w;
#pragma unroll
        for (int k1 = 0; k1 < 32; k1 += 2) {
            z[SLOT(k1, tid)]     = (k1 == 0) ? a[0] : cmul(a[BREV5[k1]], we);
            z[SLOT(k1 + 1, tid)] = cmul(a[BREV5[k1 + 1]], wo);
            we = cmul(we, w2); wo = cmul(wo, w2);
        }
    }
    __syncthreads();
    {
        const int r = tid >> 3, n2p = tid & 7;
#pragma unroll
        for (int n1p = 0; n1p < 32; ++n1p)
            a[n1p] = z[SLOT(r, (n1p << 3) + n2p)];
        fft32_dif(a);
        float2 wb = tw[n2p << 5], wb2 = cmul(wb, wb);
        float2 be = make_float2(1.f, 0.f), bo = wb;
#pragma unroll
        for (int k1p = 0; k1p < 32; k1p += 2) {
            z[SLOT(r, (k1p << 3) + n2p)]       = (k1p == 0) ? a[0] : cmul(a[BREV5[k1p]], be);
            z[SLOT(r, ((k1p + 1) << 3) + n2p)] = cmul(a[BREV5[k1p + 1]], bo);
            be = cmul(be, wb2); bo = cmul(bo, wb2);
        }
    }
    __syncthreads();
#pragma unroll
    for (int u = 0; u < 4; ++u) {
        int f = tid + (u << 8);
        int k1 = f >> 5, k1p = f & 31;
        float2 b[8];
#pragma unroll
        for (int e = 0; e < 8; ++e) b[e] = z[SLOT(k1, (k1p << 3) + e)];
        fft8_dif(b);
#pragma unroll
        for (int j = 0; j < 8; ++j) z[SLOT(k1, (k1p << 3) + j)] = b[j];
    }
    __syncthreads();

    const float sc = 0.5f / (float)N_FFT;
#pragma unroll
    for (int v = 0; v < 16; ++v) {
        int s = tid + (v << 8);
        int k1 = s >> 8, r1 = (s >> 4) & 15, j = s & 15;
        int kp = k1 + (r1 << 4) + (BREV4[j] << 8);
#pragma unroll
        for (int par = 0; par < 2; ++par) {
            int k  = 2 * kp + par;
            int km = (N_FFT - k) & (N_FFT - 1);
            float2 A = z[ZADDR(k)];
            float2 B = z[ZADDR(km)];
            float2 Bj = make_float2(B.x, -B.y);
            float2 T0 = make_float2((A.x + Bj.x) * sc, (A.y + Bj.y) * sc);
            float2 dd = csub(A, Bj);
            float2 T1 = make_float2(dd.y * sc, -dd.x * sc);
            Tc[(size_t)d0 * N_FFT + (par << 12) + s] = T0;
            Tc[(size_t)d1 * N_FFT + (par << 12) + s] = T1;
        }
    }
}

template<bool OT>
__global__ __launch_bounds__(256, 2) void conv3_kernel(const float* __restrict__ x,
                                                       const float2* __restrict__ tw,
                                                       const float2* __restrict__ Tc,
                                                       float2* __restrict__ oT,
                                                       float* __restrict__ out) {
    __shared__ float2 z[SEQ];
    const int tid = threadIdx.x;
    const int sb = (blockIdx.x & 7) * 128 + (blockIdx.x >> 3);
    const int d  = sb >> 1;
    const int pb = sb & 1;

    const float* x0 = x + (size_t)(2 * pb) * SEQ * NCH + d;
    const float* x1 = x0 + (size_t)SEQ * NCH;

    float2 a[16], ie[16];

#pragma unroll
    for (int par = 0; par < 2; ++par) {
        if (par == 1) __syncthreads();

        if (par == 0) {
#pragma unroll
            for (int n1 = 0; n1 < 16; ++n1) {
                int n = (n1 << 8) + tid;
                a[n1] = make_float2(x0[(size_t)n * NCH], x1[(size_t)n * NCH]);
            }
        } else {
#pragma unroll
            for (int n1 = 0; n1 < 16; ++n1) {
                int n = (n1 << 8) + tid;
                float2 v = make_float2(x0[(size_t)n * NCH], x1[(size_t)n * NCH]);
                a[n1] = cmul(v, tw[n]);
            }
        }
        fft16_dif(a);
        {
            float2 w = tw[2 * tid], w2 = cmul(w, w);
            float2 we = make_float2(1.f, 0.f), wo = w;
#pragma unroll
            for (int k1 = 0; k1 < 16; k1 += 2) {
                z[SLOT16(k1, tid)]     = (k1 == 0) ? a[0] : cmul(a[BREV4[k1]], we);
                z[SLOT16(k1 + 1, tid)] = cmul(a[BREV4[k1 + 1]], wo);
                we = cmul(we, w2); wo = cmul(wo, w2);
            }
        }
        __syncthreads();
        {
            const int k1 = tid >> 4, n3 = tid & 15;
#pragma unroll
            for (int n2 = 0; n2 < 16; ++n2)
                a[n2] = z[SLOT16(k1, (n2 << 4) + n3)];
            fft16_dif(a);
            float2 wb = tw[n3 << 5], wb2 = cmul(wb, wb);
            float2 be = make_float2(1.f, 0.f), bo = wb;
#pragma unroll
            for (int r1 = 0; r1 < 16; r1 += 2) {
                z[SLOT16(k1, (r1 << 4) + n3)]       = (r1 == 0) ? a[0] : cmul(a[BREV4[r1]], be);
                z[SLOT16(k1, ((r1 + 1) << 4) + n3)] = cmul(a[BREV4[r1 + 1]], bo);
                be = cmul(be, wb2); bo = cmul(bo, wb2);
            }
        }
        __syncthreads();
        {
            const int k1 = tid >> 4, r1 = tid & 15;
#pragma unroll
            for (int n3 = 0; n3 < 16; ++n3)
                a[n3] = z[SLOT16(k1, (r1 << 4) + n3)];
            fft16_dif(a);
            const float2* Td = Tc + ((size_t)d << 13) + (par << 12);
#pragma unroll
            for (int j = 0; j < 16; ++j) {
                // matches tfft2 layout: s = (k1<<8)+(r1<<4)+j
                float2 T = Td[((tid >> 4) << 8) + ((tid & 15) << 4) + j];
                a[j] = cmul(a[j], T);
            }
            ifft16_dit(a);
#pragma unroll
            for (int n3 = 0; n3 < 16; ++n3)
                z[SLOT16(k1, (r1 << 4) + n3)] = a[n3];
        }
        __syncthreads();
        {
            const int k1 = tid >> 4, n3 = tid & 15;
            float2 wb = tw[n3 << 5], wb2 = cmul(wb, wb);
            float2 be = make_float2(1.f, 0.f), bo = wb;
#pragma unroll
            for (int r1 = 0; r1 < 16; r1 += 2) {
                float2 v0 = z[SLOT16(k1, (r1 << 4) + n3)];
                float2 v1 = z[SLOT16(k1, ((r1 + 1) << 4) + n3)];
                a[BREV4[r1]]     = (r1 == 0) ? v0 : cmulj(v0, be);
                a[BREV4[r1 + 1]] = cmulj(v1, bo);
                be = cmul(be, wb2); bo = cmul(bo, wb2);
            }
            ifft16_dit(a);
#pragma unroll
            for (int n2 = 0; n2 < 16; ++n2)
                z[SLOT16(k1, (n2 << 4) + n3)] = a[n2];
        }
        __syncthreads();
        {
            float2 w = tw[2 * tid], w2 = cmul(w, w);
            float2 we = make_float2(1.f, 0.f), wo = w;
#pragma unroll
            for (int k1 = 0; k1 < 16; k1 += 2) {
                float2 v0 = z[SLOT16(k1, tid)];
                float2 v1 = z[SLOT16(k1 + 1, tid)];
                a[BREV4[k1]]     = (k1 == 0) ? v0 : cmulj(v0, we);
                a[BREV4[k1 + 1]] = cmulj(v1, wo);
                we = cmul(we, w2); wo = cmul(wo, w2);
            }
            ifft16_dit(a);
        }

        if (par == 0) {
#pragma unroll
            for (int n1 = 0; n1 < 16; ++n1) ie[n1] = a[n1];
        } else {
            if constexpr (OT) {
                float2* op = oT + (((size_t)(pb * NCH + d)) << 12);
#pragma unroll
                for (int n1 = 0; n1 < 16; ++n1) {
                    int n = (n1 << 8) + tid;
                    op[n] = cadd(ie[n1], cmulj(a[n1], tw[n]));
                }
            } else {
                float* o0 = out + (size_t)(2 * pb) * SEQ * NCH + d;
                float* o1 = o0 + (size_t)SEQ * NCH;
#pragma unroll
                for (int n1 = 0; n1 < 16; ++n1) {
                    int n = (n1 << 8) + tid;
                    float2 o = cadd(ie[n1], cmulj(a[n1], tw[n]));
                    o0[(size_t)n * NCH] = o.x;
                    o1[(size_t)n * NCH] = o.y;
                }
            }
        }
    }
}

extern "C" void kernel_launch(void* const* d_in, const int* in_sizes, int n_in,
                              void* d_out, int out_size, void* d_ws, size_t ws_size,
                              hipStream_t stream) {
    (void)in_sizes; (void)n_in; (void)out_size;
    const float* x = (const float*)d_in[0];
    const float* t = (const float*)d_in[1];
    float* out = (float*)d_out;

    float2* tw  = (float2*)d_ws;                   // 8192 f2 = 64 KB
    float2* Tc  = tw + N_FFT;                      // 512*8192 f2 = 33.55 MB
    float2* xoT = Tc + (size_t)NCH * N_FFT;        // 2*512*4096 f2 = 33.55 MB
    float2* tT  = xoT + 2ull * NCH * SEQ;          // 256*8192 f2 = 16.78 MB

    const size_t need_full = sizeof(float2) * ((size_t)N_FFT + (size_t)NCH * N_FFT
                                               + 2ull * NCH * SEQ
                                               + 256ull * N_FFT);   // ~84 MB
    const size_t need_ot   = sizeof(float2) * ((size_t)N_FFT + (size_t)NCH * N_FFT
                                               + 2ull * NCH * SEQ); // ~67.2 MB

    twiddle_init<<<N_FFT / 256, 256, 0, stream>>>(tw);
    if (ws_size >= need_full) {
        transpose_in<<<1536, 256, 0, stream>>>(x, t, xoT, tT);
        tfft3_kernel<<<NCH / 2, 256, 0, stream>>>(tT, tw, Tc);
        conv6_kernel<<<1024, 256, 0, stream>>>(xoT, tw, Tc);
        transpose_out<<<2048, 256, 0, stream>>>(xoT, out);
    } else if (ws_size >= need_ot) {
        tfft2_kernel<<<NCH / 2, 256, 0, stream>>>(t, tw, Tc);
        conv3_kernel<true><<<1024, 256, 0, stream>>>(x, tw, Tc, xoT, out);
        transpose_out<<<2048, 256, 0, stream>>>(xoT, out);
    } else {
        tfft2_kernel<<<NCH / 2, 256, 0, stream>>>(t, tw, Tc);
        conv3_kernel<false><<<1024, 256, 0, stream>>>(x, tw, Tc, nullptr, out);
    }
}

// Round 13
// 83.358 us; speedup vs baseline: 1.3642x; 1.1139x over previous
//
#include <hip/hip_runtime.h>
#include <math.h>

// Problem constants (b=4, n=m=l=4096, d=512, fft_len=8192, t_len=2l-2=8190)
#define N_FFT   8192
#define SEQ     4096
#define NCH     512
#define TLEN    8190

__device__ __forceinline__ float2 cmul(float2 a, float2 b) {
    return make_float2(a.x * b.x - a.y * b.y, a.x * b.y + a.y * b.x);
}
__device__ __forceinline__ float2 cmulj(float2 a, float2 b) {   // a * conj(b)
    return make_float2(a.x * b.x + a.y * b.y, a.y * b.x - a.x * b.y);
}
__device__ __forceinline__ float2 cadd(float2 a, float2 b) {
    return make_float2(a.x + b.x, a.y + b.y);
}
__device__ __forceinline__ float2 csub(float2 a, float2 b) {
    return make_float2(a.x - b.x, a.y - b.y);
}

// W32^j = exp(-2*pi*i*j/32), j in [0,16)
constexpr float W32C[16] = {
    1.0f, 0.9807852804032304f, 0.9238795325112867f, 0.8314696123025452f,
    0.7071067811865476f, 0.5555702330196023f, 0.3826834323650898f, 0.1950903220161283f,
    0.0f, -0.1950903220161282f, -0.3826834323650897f, -0.5555702330196020f,
    -0.7071067811865475f, -0.8314696123025453f, -0.9238795325112867f, -0.9807852804032304f
};
constexpr float W32S[16] = {
    -0.0f, -0.1950903220161283f, -0.3826834323650898f, -0.5555702330196022f,
    -0.7071067811865476f, -0.8314696123025452f, -0.9238795325112867f, -0.9807852804032304f,
    -1.0f, -0.9807852804032304f, -0.9238795325112867f, -0.8314696123025453f,
    -0.7071067811865476f, -0.5555702330196022f, -0.3826834323650899f, -0.1950903220161286f
};

constexpr int BREV5[32] = {0,16,8,24,4,20,12,28,2,18,10,26,6,22,14,30,
                           1,17,9,25,5,21,13,29,3,19,11,27,7,23,15,31};
constexpr int BREV4[16] = {0,8,4,12,2,10,6,14,1,9,5,13,3,11,7,15};

__device__ __forceinline__ int brev3i(int b) {
    return ((b & 1) << 2) | (b & 2) | ((b & 4) >> 2);
}

// ------------------------------------------------ specialized butterflies ---
// DIF: x0' = x0+x1; x1' = (x0-x1) * W32^E. E=0 -> copy; E=8 -> *( -i ).
template<int E>
__device__ __forceinline__ void bfly_dif(float2& x0, float2& x1) {
    float2 s = csub(x0, x1);
    x0 = cadd(x0, x1);
    if constexpr (E == 0)       x1 = s;
    else if constexpr (E == 8)  x1 = make_float2(s.y, -s.x);
    else                        x1 = cmul(s, make_float2(W32C[E], W32S[E]));
}
// DIT (inverse, W^+): t = x1 * conj(W32^E); x0' = x0+t; x1' = x0-t.
template<int E>
__device__ __forceinline__ void bfly_dit(float2& x0, float2& x1) {
    float2 t;
    if constexpr (E == 0)       t = x1;
    else if constexpr (E == 8)  t = make_float2(-x1.y, x1.x);   // * (+i)
    else                        t = cmulj(x1, make_float2(W32C[E], W32S[E]));
    float2 x0o = x0;
    x0 = cadd(x0o, t);
    x1 = csub(x0o, t);
}

// ---------------------------------------------------------------- reg FFTs ---
__device__ __forceinline__ void fft32_dif(float2 a[32]) {
#pragma unroll
    for (int s = 4; s >= 0; --s) {
        const int h = 1 << s;
#pragma unroll
        for (int g = 0; g < 32; g += 2 * h) {
#pragma unroll
            for (int i = 0; i < h; ++i) {
                float2 x0 = a[g + i], x1 = a[g + i + h];
                a[g + i] = cadd(x0, x1);
                float2 w = make_float2(W32C[i << (4 - s)], W32S[i << (4 - s)]);
                a[g + i + h] = cmul(csub(x0, x1), w);
            }
        }
    }
}

// fft16 DIF, natural in -> a[j] = A[brev4(j)], trivial twiddles specialized
__device__ __forceinline__ void fft16_dif(float2 a[16]) {
    // s=3 (h=8), E = 2i
    bfly_dif<0>(a[0],a[8]);   bfly_dif<2>(a[1],a[9]);
    bfly_dif<4>(a[2],a[10]);  bfly_dif<6>(a[3],a[11]);
    bfly_dif<8>(a[4],a[12]);  bfly_dif<10>(a[5],a[13]);
    bfly_dif<12>(a[6],a[14]); bfly_dif<14>(a[7],a[15]);
    // s=2 (h=4), E = 4i
    bfly_dif<0>(a[0],a[4]);   bfly_dif<4>(a[1],a[5]);
    bfly_dif<8>(a[2],a[6]);   bfly_dif<12>(a[3],a[7]);
    bfly_dif<0>(a[8],a[12]);  bfly_dif<4>(a[9],a[13]);
    bfly_dif<8>(a[10],a[14]); bfly_dif<12>(a[11],a[15]);
    // s=1 (h=2), E = 8i
    bfly_dif<0>(a[0],a[2]);   bfly_dif<8>(a[1],a[3]);
    bfly_dif<0>(a[4],a[6]);   bfly_dif<8>(a[5],a[7]);
    bfly_dif<0>(a[8],a[10]);  bfly_dif<8>(a[9],a[11]);
    bfly_dif<0>(a[12],a[14]); bfly_dif<8>(a[13],a[15]);
    // s=0 (h=1), all identity
    bfly_dif<0>(a[0],a[1]);   bfly_dif<0>(a[2],a[3]);
    bfly_dif<0>(a[4],a[5]);   bfly_dif<0>(a[6],a[7]);
    bfly_dif<0>(a[8],a[9]);   bfly_dif<0>(a[10],a[11]);
    bfly_dif<0>(a[12],a[13]); bfly_dif<0>(a[14],a[15]);
}

// ifft16 DIT, input a[j] = In[brev4(j)] -> natural out, unnormalized
__device__ __forceinline__ void ifft16_dit(float2 a[16]) {
    // s=0
    bfly_dit<0>(a[0],a[1]);   bfly_dit<0>(a[2],a[3]);
    bfly_dit<0>(a[4],a[5]);   bfly_dit<0>(a[6],a[7]);
    bfly_dit<0>(a[8],a[9]);   bfly_dit<0>(a[10],a[11]);
    bfly_dit<0>(a[12],a[13]); bfly_dit<0>(a[14],a[15]);
    // s=1, E = 8i
    bfly_dit<0>(a[0],a[2]);   bfly_dit<8>(a[1],a[3]);
    bfly_dit<0>(a[4],a[6]);   bfly_dit<8>(a[5],a[7]);
    bfly_dit<0>(a[8],a[10]);  bfly_dit<8>(a[9],a[11]);
    bfly_dit<0>(a[12],a[14]); bfly_dit<8>(a[13],a[15]);
    // s=2, E = 4i
    bfly_dit<0>(a[0],a[4]);   bfly_dit<4>(a[1],a[5]);
    bfly_dit<8>(a[2],a[6]);   bfly_dit<12>(a[3],a[7]);
    bfly_dit<0>(a[8],a[12]);  bfly_dit<4>(a[9],a[13]);
    bfly_dit<8>(a[10],a[14]); bfly_dit<12>(a[11],a[15]);
    // s=3, E = 2i
    bfly_dit<0>(a[0],a[8]);   bfly_dit<2>(a[1],a[9]);
    bfly_dit<4>(a[2],a[10]);  bfly_dit<6>(a[3],a[11]);
    bfly_dit<8>(a[4],a[12]);  bfly_dit<10>(a[5],a[13]);
    bfly_dit<12>(a[6],a[14]); bfly_dit<14>(a[7],a[15]);
}

__device__ __forceinline__ void fft8_dif(float2 a[8]) {
#pragma unroll
    for (int s = 2; s >= 0; --s) {
        const int h = 1 << s;
#pragma unroll
        for (int g = 0; g < 8; g += 2 * h) {
#pragma unroll
            for (int i = 0; i < h; ++i) {
                float2 x0 = a[g + i], x1 = a[g + i + h];
                a[g + i] = cadd(x0, x1);
                int e = (i << (2 - s)) << 2;   // W8^m = W32^{4m}
                float2 w = make_float2(W32C[e], W32S[e]);
                a[g + i + h] = cmul(csub(x0, x1), w);
            }
        }
    }
}

// bank-conflict-reduced LDS slot, 32-row layout (tfft)
__device__ __forceinline__ int SLOT(int r, int c) {
    return (r << 8) + (c ^ ((c >> 4) & 7) ^ ((r & 1) << 3));
}
// LDS slot of frequency bin q after tfft forward stage C
__device__ __forceinline__ int ZADDR(int q) {
    return SLOT(q & 31, (((q >> 5) & 31) << 3) + brev3i((q >> 10) & 7));
}
// 16-row layout (conv)
__device__ __forceinline__ int SLOT16(int r, int c) {
    return (r << 8) + (c ^ ((c >> 4) & 7) ^ ((r & 1) << 3));
}

// ---------------------------------------------------------------- twiddles ---
__global__ __launch_bounds__(256) void twiddle_init(float2* __restrict__ tw) {
    int k = blockIdx.x * 256 + threadIdx.x;
    double th = -2.0 * 3.14159265358979323846 * (double)k / (double)N_FFT;
    tw[k] = make_float2((float)cos(th), (float)sin(th));
}

// ---------------------------------------------------------------- transposes -
// Fused input transposes + twiddle table.
// bid < 1024:        x[b][n][d] -> xT[pb][d][n]  (64n x 64d tiles, float4)
// 1024 <= bid <1536: t[n][d] -> tT[dp][n] (zero-padded to 8192)
// bid >= 1536:       twiddle table (32 blocks)
__global__ __launch_bounds__(256) void transpose_in(const float* __restrict__ x,
                                                    const float* __restrict__ t,
                                                    float2* __restrict__ xT,
                                                    float2* __restrict__ tT,
                                                    float2* __restrict__ tw) {
    __shared__ float tX[64][65], tY[64][65];
    const int tid = threadIdx.x;
    if (blockIdx.x >= 1536) {
        int k = (blockIdx.x - 1536) * 256 + tid;
        double th = -2.0 * 3.14159265358979323846 * (double)k / (double)N_FFT;
        tw[k] = make_float2((float)cos(th), (float)sin(th));
        return;
    }
    if (blockIdx.x < 1024) {
        const int bid = blockIdx.x;        // [pb:2][dt:8][nt:64]
        const int pb = bid >> 9;
        const int dt = (bid >> 6) & 7;
        const int nt = bid & 63;
        const int d0 = dt << 6, n0 = nt << 6;
        const float* x0 = x + (size_t)(2 * pb) * SEQ * NCH;
        const float* x1 = x0 + (size_t)SEQ * NCH;
        {
            const int c4 = tid & 15, r16 = tid >> 4;   // 16 float4 cols, 16 rows
#pragma unroll
            for (int it = 0; it < 4; ++it) {
                int row = r16 + (it << 4);
                size_t off = (size_t)(n0 + row) * NCH + d0 + (c4 << 2);
                float4 v0 = *(const float4*)(x0 + off);
                float4 v1 = *(const float4*)(x1 + off);
                tX[row][(c4 << 2) + 0] = v0.x; tX[row][(c4 << 2) + 1] = v0.y;
                tX[row][(c4 << 2) + 2] = v0.z; tX[row][(c4 << 2) + 3] = v0.w;
                tY[row][(c4 << 2) + 0] = v1.x; tY[row][(c4 << 2) + 1] = v1.y;
                tY[row][(c4 << 2) + 2] = v1.z; tY[row][(c4 << 2) + 3] = v1.w;
            }
        }
        __syncthreads();
        {
            const int nc = tid & 63, dr4 = tid >> 6;
#pragma unroll
            for (int it = 0; it < 16; ++it) {
                int dr = dr4 + (it << 2);
                xT[(((size_t)(pb * NCH + d0 + dr)) << 12) + n0 + nc] =
                    make_float2(tX[nc][dr], tY[nc][dr]);
            }
        }
    } else {
        const int bid = blockIdx.x - 1024; // [nt:128][dpt:4]
        const int nt = bid >> 2, dpt = bid & 3;
        const int n0 = nt << 6, dp0 = dpt << 6;
        {
            const int c = tid & 63, r4 = tid >> 6;
#pragma unroll
            for (int it = 0; it < 16; ++it) {
                int row = r4 + (it << 2);
                int nn = n0 + row;
                float2 v = make_float2(0.f, 0.f);
                if (nn < TLEN)
                    v = *(const float2*)(t + (size_t)nn * NCH + ((dp0 + c) << 1));
                tX[row][c] = v.x;
                tY[row][c] = v.y;
            }
        }
        __syncthreads();
        {
            const int nc = tid & 63, dr4 = tid >> 6;
#pragma unroll
            for (int it = 0; it < 16; ++it) {
                int dr = dr4 + (it << 2);
                tT[(((size_t)(dp0 + dr)) << 13) + n0 + nc] =
                    make_float2(tX[nc][dr], tY[nc][dr]);
            }
        }
    }
}

// ---------------------------------------------------------------- t spectra --
// Monolithic 8192 FFT (32x32x8), channels d0=2*bid, d1=2*bid+1 packed, input
// from tT (coalesced). Emits parity-split spectrum in WAVE-CONTIGUOUS chunk
// layout: f2 position p = (q<<9) + 2*t + e holds bin for conv-thread t's
// a[j], j = 2q+e: kp = (t>>4) + ((t&15)<<4) + (BREV4[j]<<8). Prescaled 1/8192.
__global__ __launch_bounds__(256) void tfft3_kernel(const float2* __restrict__ tT,
                                                    const float2* __restrict__ tw,
                                                    float2* __restrict__ Tc) {
    __shared__ float2 z[N_FFT];
    const int tid = threadIdx.x;
    const int d0 = blockIdx.x * 2;
    const int d1 = d0 + 1;
    const float2* tp = tT + ((size_t)blockIdx.x << 13);

    float2 a[32];
#pragma unroll
    for (int n1 = 0; n1 < 32; ++n1)
        a[n1] = tp[(n1 << 8) + tid];
    fft32_dif(a);
    {   // twiddle w^k1, w = tw[tid]; even/odd incremental chains
        float2 w = tw[tid], w2 = cmul(w, w);
        float2 we = make_float2(1.f, 0.f), wo = w;
#pragma unroll
        for (int k1 = 0; k1 < 32; k1 += 2) {
            z[SLOT(k1, tid)]     = (k1 == 0) ? a[0] : cmul(a[BREV5[k1]], we);
            z[SLOT(k1 + 1, tid)] = cmul(a[BREV5[k1 + 1]], wo);
            we = cmul(we, w2); wo = cmul(wo, w2);
        }
    }
    __syncthreads();

    {   // step B
        const int r = tid >> 3, n2p = tid & 7;
#pragma unroll
        for (int n1p = 0; n1p < 32; ++n1p)
            a[n1p] = z[SLOT(r, (n1p << 3) + n2p)];
        fft32_dif(a);
        float2 wb = tw[n2p << 5], wb2 = cmul(wb, wb);
        float2 be = make_float2(1.f, 0.f), bo = wb;
#pragma unroll
        for (int k1p = 0; k1p < 32; k1p += 2) {
            z[SLOT(r, (k1p << 3) + n2p)]       = (k1p == 0) ? a[0] : cmul(a[BREV5[k1p]], be);
            z[SLOT(r, ((k1p + 1) << 3) + n2p)] = cmul(a[BREV5[k1p + 1]], bo);
            be = cmul(be, wb2); bo = cmul(bo, wb2);
        }
    }
    __syncthreads();

    // step C: 8-point FFTs
#pragma unroll
    for (int u = 0; u < 4; ++u) {
        int f = tid + (u << 8);
        int k1 = f >> 5, k1p = f & 31;
        float2 b[8];
#pragma unroll
        for (int e = 0; e < 8; ++e) b[e] = z[SLOT(k1, (k1p << 3) + e)];
        fft8_dif(b);
#pragma unroll
        for (int j = 0; j < 8; ++j) z[SLOT(k1, (k1p << 3) + j)] = b[j];
    }
    __syncthreads();

    // Hermitian unpack, iterated output-position-major (coalesced writes)
    const float sc = 0.5f / (float)N_FFT;   // fold in ifft 1/N
#pragma unroll
    for (int v = 0; v < 16; ++v) {
        int p = tid + (v << 8);                 // f2 position in [0,4096)
        int q   = p >> 9;
        int rem = p & 511;
        int t_  = rem >> 1, e = rem & 1;
        int j_  = (q << 1) + e;
        int kp  = (t_ >> 4) + ((t_ & 15) << 4) + (BREV4[j_] << 8);
#pragma unroll
        for (int par = 0; par < 2; ++par) {
            int k  = 2 * kp + par;
            int km = (N_FFT - k) & (N_FFT - 1);
            float2 A = z[ZADDR(k)];
            float2 B = z[ZADDR(km)];
            float2 Bj = make_float2(B.x, -B.y);
            float2 T0 = make_float2((A.x + Bj.x) * sc, (A.y + Bj.y) * sc);
            float2 dd = csub(A, Bj);
            float2 T1 = make_float2(dd.y * sc, -dd.x * sc);
            Tc[(size_t)d0 * N_FFT + (par << 12) + p] = T0;
            Tc[(size_t)d1 * N_FFT + (par << 12) + p] = T1;
        }
    }
}

// ---------------------------------------------------------------- main conv --
// conv6: grid 1024, one (d, pb) per 256-thread block, 40 KB LDS -> 4
// blocks/CU, desynced phases. Specialized fft16 (trivial twiddles free) +
// Tc prefetch in two register halves (issued under stage A/B latency).
__global__ __launch_bounds__(256, 2) void conv6_kernel(float2* __restrict__ xoT,
                                                       const float2* __restrict__ tw,
                                                       const float2* __restrict__ Tc) {
    __shared__ float2 z[SEQ];          // 32 KB: 16 rows x 256 cols
    __shared__ float2 zx[1024];        // 8 KB: U_e[12..15] parking
    const int t = threadIdx.x;
    // XCD swizzle; pb-pair of each d lands in the same chunk (Tc L2 reuse)
    const int sb = (blockIdx.x & 7) * 128 + (blockIdx.x >> 3);
    const int d  = sb >> 1;
    const int pb = sb & 1;
    float2* xp  = xoT + ((size_t)(pb * NCH + d) << 12);

    float2 a[16], ie[12];

#pragma unroll
    for (int par = 0; par < 2; ++par) {
        const float4* tp = (const float4*)(Tc + ((size_t)d << 13) + (par << 12));
        float4 tf0, tf1, tf2, tf3, tf4, tf5, tf6, tf7;

        // ---- stage A: load row (+modulate for odd chain), fft16, twiddle
        if (par == 0) {
#pragma unroll
            for (int n1 = 0; n1 < 16; ++n1)
                a[n1] = xp[(n1 << 8) + t];
        } else {
#pragma unroll
            for (int n1 = 0; n1 < 16; ++n1)
                a[n1] = cmul(xp[(n1 << 8) + t], tw[(n1 << 8) + t]);
        }
        fft16_dif(a);
        {
            float2 w = tw[2 * t];        // W_4096^t
            float2 w2 = cmul(w, w);
            float2 we = make_float2(1.f, 0.f), wo = w;
#pragma unroll
            for (int k1 = 0; k1 < 16; k1 += 2) {
                z[SLOT16(k1, t)]     = (k1 == 0) ? a[0] : cmul(a[BREV4[k1]], we);
                z[SLOT16(k1 + 1, t)] = cmul(a[BREV4[k1 + 1]], wo);
                we = cmul(we, w2); wo = cmul(wo, w2);
            }
        }
        // prefetch first half of Tc (latency hidden under barrier + stage B)
        tf0 = tp[t]; tf1 = tp[256 + t]; tf2 = tp[512 + t]; tf3 = tp[768 + t];
        __syncthreads();                 // A writes read cross-thread by B

        // ---- stage B: FFT16 over n2 for (k1, n3)
        {
            const int k1 = t >> 4, n3 = t & 15;
#pragma unroll
            for (int n2 = 0; n2 < 16; ++n2)
                a[n2] = z[SLOT16(k1, (n2 << 4) + n3)];
            fft16_dif(a);
            float2 wb = tw[n3 << 5];     // W_256^{n3}
            float2 wb2 = cmul(wb, wb);
            float2 be = make_float2(1.f, 0.f), bo = wb;
#pragma unroll
            for (int r1 = 0; r1 < 16; r1 += 2) {
                z[SLOT16(k1, (r1 << 4) + n3)]       = (r1 == 0) ? a[0] : cmul(a[BREV4[r1]], be);
                z[SLOT16(k1, ((r1 + 1) << 4) + n3)] = cmul(a[BREV4[r1 + 1]], bo);
                be = cmul(be, wb2); bo = cmul(bo, wb2);
            }
        }
        // prefetch second half of Tc (hidden under stage C's fft16)
        tf4 = tp[1024 + t]; tf5 = tp[1280 + t]; tf6 = tp[1536 + t]; tf7 = tp[1792 + t];
        // B->C exchange stays inside tids [16*k1, 16*k1+15] (one wave)
        __builtin_amdgcn_sched_barrier(0);

        // ---- stage C fwd + pointwise + stage C inverse
        {
            const int k1 = t >> 4, r1 = t & 15;
#pragma unroll
            for (int n3 = 0; n3 < 16; ++n3)
                a[n3] = z[SLOT16(k1, (r1 << 4) + n3)];
            fft16_dif(a);
            a[0]  = cmul(a[0],  make_float2(tf0.x, tf0.y));
            a[1]  = cmul(a[1],  make_float2(tf0.z, tf0.w));
            a[2]  = cmul(a[2],  make_float2(tf1.x, tf1.y));
            a[3]  = cmul(a[3],  make_float2(tf1.z, tf1.w));
            a[4]  = cmul(a[4],  make_float2(tf2.x, tf2.y));
            a[5]  = cmul(a[5],  make_float2(tf2.z, tf2.w));
            a[6]  = cmul(a[6],  make_float2(tf3.x, tf3.y));
            a[7]  = cmul(a[7],  make_float2(tf3.z, tf3.w));
            a[8]  = cmul(a[8],  make_float2(tf4.x, tf4.y));
            a[9]  = cmul(a[9],  make_float2(tf4.z, tf4.w));
            a[10] = cmul(a[10], make_float2(tf5.x, tf5.y));
            a[11] = cmul(a[11], make_float2(tf5.z, tf5.w));
            a[12] = cmul(a[12], make_float2(tf6.x, tf6.y));
            a[13] = cmul(a[13], make_float2(tf6.z, tf6.w));
            a[14] = cmul(a[14], make_float2(tf7.x, tf7.y));
            a[15] = cmul(a[15], make_float2(tf7.z, tf7.w));
            ifft16_dit(a);               // DIF output order == DIT input order
#pragma unroll
            for (int n3 = 0; n3 < 16; ++n3)
                z[SLOT16(k1, (r1 << 4) + n3)] = a[n3];
        }
        __builtin_amdgcn_sched_barrier(0);   // C->Binv: same 16-lane group

        // ---- stage B inverse
        {
            const int k1 = t >> 4, n3 = t & 15;
            float2 wb = tw[n3 << 5], wb2 = cmul(wb, wb);
            float2 be = make_float2(1.f, 0.f), bo = wb;
#pragma unroll
            for (int r1 = 0; r1 < 16; r1 += 2) {
                float2 v0 = z[SLOT16(k1, (r1 << 4) + n3)];
                float2 v1 = z[SLOT16(k1, ((r1 + 1) << 4) + n3)];
                a[BREV4[r1]]     = (r1 == 0) ? v0 : cmulj(v0, be);
                a[BREV4[r1 + 1]] = cmulj(v1, bo);
                be = cmul(be, wb2); bo = cmul(bo, wb2);
            }
            ifft16_dit(a);
#pragma unroll
            for (int n2 = 0; n2 < 16; ++n2)
                z[SLOT16(k1, (n2 << 4) + n3)] = a[n2];
        }
        __syncthreads();                 // Binv writes read cross-thread by Ainv

        // ---- stage A inverse (thread-private column slots)
        {
            float2 w = tw[2 * t], w2 = cmul(w, w);
            float2 we = make_float2(1.f, 0.f), wo = w;
#pragma unroll
            for (int k1 = 0; k1 < 16; k1 += 2) {
                float2 v0 = z[SLOT16(k1, t)];
                float2 v1 = z[SLOT16(k1 + 1, t)];
                a[BREV4[k1]]     = (k1 == 0) ? v0 : cmulj(v0, we);
                a[BREV4[k1 + 1]] = cmulj(v1, wo);
                we = cmul(we, w2); wo = cmul(wo, w2);
            }
            ifft16_dit(a);               // a[n1] = U_par[n1*256 + t]
        }
        // no barrier: next chain's A-writes are column-private vs Ainv reads;
        // zx write/read is same-thread.

        if (par == 0) {
#pragma unroll
            for (int n1 = 0; n1 < 12; ++n1) ie[n1] = a[n1];
#pragma unroll
            for (int n1 = 12; n1 < 16; ++n1)
                zx[((n1 - 12) << 8) + t] = a[n1];
        } else {
            // combine o[n] = U_e[n] + conj(w[n]) * U_o[n]
#pragma unroll
            for (int n1 = 0; n1 < 12; ++n1) {
                int n = (n1 << 8) + t;
                xp[n] = cadd(ie[n1], cmulj(a[n1], tw[n]));
            }
#pragma unroll
            for (int n1 = 12; n1 < 16; ++n1) {
                int n = (n1 << 8) + t;
                float2 ue = zx[((n1 - 12) << 8) + t];
                xp[n] = cadd(ue, cmulj(a[n1], tw[n]));
            }
        }
    }
}

// ---------------------------------------------------------------- transpose --
// oT[pb][d][n] (float2: {b=2pb, b=2pb+1}) -> out[b][n][d]. LDS-tiled 32d x 64n.
__global__ __launch_bounds__(256) void transpose_out(const float2* __restrict__ oT,
                                                     float* __restrict__ out) {
    __shared__ float2 tile[32][65];
    const int tid = threadIdx.x;
    const int bid = blockIdx.x;
    const int pb = bid >> 10;
    const int dt = (bid >> 6) & 15;
    const int nt = bid & 63;
    const int d0 = dt << 5, n0 = nt << 6;

    {
        const int nl = tid & 63, dl = tid >> 6;
#pragma unroll
        for (int i = 0; i < 8; ++i) {
            int dd = dl + (i << 2);
            tile[dd][nl] = oT[(((size_t)(pb * NCH + d0 + dd)) << 12) + n0 + nl];
        }
    }
    __syncthreads();
    {
        const int dl = tid & 31, ns = tid >> 5;
        float* o0 = out + (size_t)(2 * pb) * SEQ * NCH;
        float* o1 = o0 + (size_t)SEQ * NCH;
#pragma unroll
        for (int j = 0; j < 8; ++j) {
            int nn = n0 + ns + (j << 3);
            float2 v = tile[dl][ns + (j << 3)];
            o0[(size_t)nn * NCH + d0 + dl] = v.x;
            o1[(size_t)nn * NCH + d0 + dl] = v.y;
        }
    }
}

// =================== fallback path (small ws) ===============================
__global__ __launch_bounds__(256) void tfft2_kernel(const float* __restrict__ t,
                                                    const float2* __restrict__ tw,
                                                    float2* __restrict__ Tc) {
    __shared__ float2 z[N_FFT];
    const int tid = threadIdx.x;
    const int d0 = blockIdx.x * 2;
    const int d1 = d0 + 1;

    float2 a[32];
#pragma unroll
    for (int n1 = 0; n1 < 32; ++n1) {
        int n = (n1 << 8) + tid;
        float va = 0.f, vb = 0.f;
        if (n < TLEN) {
            va = t[(size_t)n * NCH + d0];
            vb = t[(size_t)n * NCH + d1];
        }
        a[n1] = make_float2(va, vb);
    }
    fft32_dif(a);
    {
        float2 w = tw[tid], w2 = cmul(w, w);
        float2 we = make_float2(1.f, 0.f), wo = w;
#pragma unroll
        for (int k1 = 0; k1 < 32; k1 += 2) {
            z[SLOT(k1, tid)]     = (k1 == 0) ? a[0] : cmul(a[BREV5[k1]], we);
            z[SLOT(k1 + 1, tid)] = cmul(a[BREV5[k1 + 1]], wo);
            we = cmul(we, w2); wo = cmul(wo, w2);
        }
    }
    __syncthreads();
    {
        const int r = tid >> 3, n2p = tid & 7;
#pragma unroll
        for (int n1p = 0; n1p < 32; ++n1p)
            a[n1p] = z[SLOT(r, (n1p << 3) + n2p)];
        fft32_dif(a);
        float2 wb = tw[n2p << 5], wb2 = cmul(wb, wb);
        float2 be = make_float2(1.f, 0.f), bo = wb;
#pragma unroll
        for (int k1p = 0; k1p < 32; k1p += 2) {
            z[SLOT(r, (k1p << 3) + n2p)]       = (k1p == 0) ? a[0] : cmul(a[BREV5[k1p]], be);
            z[SLOT(r, ((k1p + 1) << 3) + n2p)] = cmul(a[BREV5[k1p + 1]], bo);
            be = cmul(be, wb2); bo = cmul(bo, wb2);
        }
    }
    __syncthreads();
#pragma unroll
    for (int u = 0; u < 4; ++u) {
        int f = tid + (u << 8);
        int k1 = f >> 5, k1p = f & 31;
        float2 b[8];
#pragma unroll
        for (int e = 0; e < 8; ++e) b[e] = z[SLOT(k1, (k1p << 3) + e)];
        fft8_dif(b);
#pragma unroll
        for (int j = 0; j < 8; ++j) z[SLOT(k1, (k1p << 3) + j)] = b[j];
    }
    __syncthreads();

    const float sc = 0.5f / (float)N_FFT;
#pragma unroll
    for (int v = 0; v < 16; ++v) {
        int s = tid + (v << 8);
        int k1 = s >> 8, r1 = (s >> 4) & 15, j = s & 15;
        int kp = k1 + (r1 << 4) + (BREV4[j] << 8);
#pragma unroll
        for (int par = 0; par < 2; ++par) {
            int k  = 2 * kp + par;
            int km = (N_FFT - k) & (N_FFT - 1);
            float2 A = z[ZADDR(k)];
            float2 B = z[ZADDR(km)];
            float2 Bj = make_float2(B.x, -B.y);
            float2 T0 = make_float2((A.x + Bj.x) * sc, (A.y + Bj.y) * sc);
            float2 dd = csub(A, Bj);
            float2 T1 = make_float2(dd.y * sc, -dd.x * sc);
            Tc[(size_t)d0 * N_FFT + (par << 12) + s] = T0;
            Tc[(size_t)d1 * N_FFT + (par << 12) + s] = T1;
        }
    }
}

template<bool OT>
__global__ __launch_bounds__(256, 2) void conv3_kernel(const float* __restrict__ x,
                                                       const float2* __restrict__ tw,
                                                       const float2* __restrict__ Tc,
                                                       float2* __restrict__ oT,
                                                       float* __restrict__ out) {
    __shared__ float2 z[SEQ];
    const int tid = threadIdx.x;
    const int sb = (blockIdx.x & 7) * 128 + (blockIdx.x >> 3);
    const int d  = sb >> 1;
    const int pb = sb & 1;

    const float* x0 = x + (size_t)(2 * pb) * SEQ * NCH + d;
    const float* x1 = x0 + (size_t)SEQ * NCH;

    float2 a[16], ie[16];

#pragma unroll
    for (int par = 0; par < 2; ++par) {
        if (par == 1) __syncthreads();

        if (par == 0) {
#pragma unroll
            for (int n1 = 0; n1 < 16; ++n1) {
                int n = (n1 << 8) + tid;
                a[n1] = make_float2(x0[(size_t)n * NCH], x1[(size_t)n * NCH]);
            }
        } else {
#pragma unroll
            for (int n1 = 0; n1 < 16; ++n1) {
                int n = (n1 << 8) + tid;
                float2 v = make_float2(x0[(size_t)n * NCH], x1[(size_t)n * NCH]);
                a[n1] = cmul(v, tw[n]);
            }
        }
        fft16_dif(a);
        {
            float2 w = tw[2 * tid], w2 = cmul(w, w);
            float2 we = make_float2(1.f, 0.f), wo = w;
#pragma unroll
            for (int k1 = 0; k1 < 16; k1 += 2) {
                z[SLOT16(k1, tid)]     = (k1 == 0) ? a[0] : cmul(a[BREV4[k1]], we);
                z[SLOT16(k1 + 1, tid)] = cmul(a[BREV4[k1 + 1]], wo);
                we = cmul(we, w2); wo = cmul(wo, w2);
            }
        }
        __syncthreads();
        {
            const int k1 = tid >> 4, n3 = tid & 15;
#pragma unroll
            for (int n2 = 0; n2 < 16; ++n2)
                a[n2] = z[SLOT16(k1, (n2 << 4) + n3)];
            fft16_dif(a);
            float2 wb = tw[n3 << 5], wb2 = cmul(wb, wb);
            float2 be = make_float2(1.f, 0.f), bo = wb;
#pragma unroll
            for (int r1 = 0; r1 < 16; r1 += 2) {
                z[SLOT16(k1, (r1 << 4) + n3)]       = (r1 == 0) ? a[0] : cmul(a[BREV4[r1]], be);
                z[SLOT16(k1, ((r1 + 1) << 4) + n3)] = cmul(a[BREV4[r1 + 1]], bo);
                be = cmul(be, wb2); bo = cmul(bo, wb2);
            }
        }
        __syncthreads();
        {
            const int k1 = tid >> 4, r1 = tid & 15;
#pragma unroll
            for (int n3 = 0; n3 < 16; ++n3)
                a[n3] = z[SLOT16(k1, (r1 << 4) + n3)];
            fft16_dif(a);
            const float2* Td = Tc + ((size_t)d << 13) + (par << 12);
#pragma unroll
            for (int j = 0; j < 16; ++j) {
                float2 T = Td[((tid >> 4) << 8) + ((tid & 15) << 4) + j];
                a[j] = cmul(a[j], T);
            }
            ifft16_dit(a);
#pragma unroll
            for (int n3 = 0; n3 < 16; ++n3)
                z[SLOT16(k1, (r1 << 4) + n3)] = a[n3];
        }
        __syncthreads();
        {
            const int k1 = tid >> 4, n3 = tid & 15;
            float2 wb = tw[n3 << 5], wb2 = cmul(wb, wb);
            float2 be = make_float2(1.f, 0.f), bo = wb;
#pragma unroll
            for (int r1 = 0; r1 < 16; r1 += 2) {
                float2 v0 = z[SLOT16(k1, (r1 << 4) + n3)];
                float2 v1 = z[SLOT16(k1, ((r1 + 1) << 4) + n3)];
                a[BREV4[r1]]     = (r1 == 0) ? v0 : cmulj(v0, be);
                a[BREV4[r1 + 1]] = cmulj(v1, bo);
                be = cmul(be, wb2); bo = cmul(bo, wb2);
            }
            ifft16_dit(a);
#pragma unroll
            for (int n2 = 0; n2 < 16; ++n2)
                z[SLOT16(k1, (n2 << 4) + n3)] = a[n2];
        }
        __syncthreads();
        {
            float2 w = tw[2 * tid], w2 = cmul(w, w);
            float2 we = make_float2(1.f, 0.f), wo = w;
#pragma unroll
            for (int k1 = 0; k1 < 16; k1 += 2) {
                float2 v0 = z[SLOT16(k1, tid)];
                float2 v1 = z[SLOT16(k1 + 1, tid)];
                a[BREV4[k1]]     = (k1 == 0) ? v0 : cmulj(v0, we);
                a[BREV4[k1 + 1]] = cmulj(v1, wo);
                we = cmul(we, w2); wo = cmul(wo, w2);
            }
            ifft16_dit(a);
        }

        if (par == 0) {
#pragma unroll
            for (int n1 = 0; n1 < 16; ++n1) ie[n1] = a[n1];
        } else {
            if constexpr (OT) {
                float2* op = oT + (((size_t)(pb * NCH + d)) << 12);
#pragma unroll
                for (int n1 = 0; n1 < 16; ++n1) {
                    int n = (n1 << 8) + tid;
                    op[n] = cadd(ie[n1], cmulj(a[n1], tw[n]));
                }
            } else {
                float* o0 = out + (size_t)(2 * pb) * SEQ * NCH + d;
                float* o1 = o0 + (size_t)SEQ * NCH;
#pragma unroll
                for (int n1 = 0; n1 < 16; ++n1) {
                    int n = (n1 << 8) + tid;
                    float2 o = cadd(ie[n1], cmulj(a[n1], tw[n]));
                    o0[(size_t)n * NCH] = o.x;
                    o1[(size_t)n * NCH] = o.y;
                }
            }
        }
    }
}

extern "C" void kernel_launch(void* const* d_in, const int* in_sizes, int n_in,
                              void* d_out, int out_size, void* d_ws, size_t ws_size,
                              hipStream_t stream) {
    (void)in_sizes; (void)n_in; (void)out_size;
    const float* x = (const float*)d_in[0];
    const float* t = (const float*)d_in[1];
    float* out = (float*)d_out;

    float2* tw  = (float2*)d_ws;                   // 8192 f2 = 64 KB
    float2* Tc  = tw + N_FFT;                      // 512*8192 f2 = 33.55 MB
    float2* xoT = Tc + (size_t)NCH * N_FFT;        // 2*512*4096 f2 = 33.55 MB
    float2* tT  = xoT + 2ull * NCH * SEQ;          // 256*8192 f2 = 16.78 MB

    const size_t need_full = sizeof(float2) * ((size_t)N_FFT + (size_t)NCH * N_FFT
                                               + 2ull * NCH * SEQ
                                               + 256ull * N_FFT);   // ~84 MB
    const size_t need_ot   = sizeof(float2) * ((size_t)N_FFT + (size_t)NCH * N_FFT
                                               + 2ull * NCH * SEQ); // ~67.2 MB

    if (ws_size >= need_full) {
        transpose_in<<<1568, 256, 0, stream>>>(x, t, xoT, tT, tw);
        tfft3_kernel<<<NCH / 2, 256, 0, stream>>>(tT, tw, Tc);
        conv6_kernel<<<1024, 256, 0, stream>>>(xoT, tw, Tc);
        transpose_out<<<2048, 256, 0, stream>>>(xoT, out);
    } else if (ws_size >= need_ot) {
        twiddle_init<<<N_FFT / 256, 256, 0, stream>>>(tw);
        tfft2_kernel<<<NCH / 2, 256, 0, stream>>>(t, tw, Tc);
        conv3_kernel<true><<<1024, 256, 0, stream>>>(x, tw, Tc, xoT, out);
        transpose_out<<<2048, 256, 0, stream>>>(xoT, out);
    } else {
        twiddle_init<<<N_FFT / 256, 256, 0, stream>>>(tw);
        tfft2_kernel<<<NCH / 2, 256, 0, stream>>>(t, tw, Tc);
        conv3_kernel<false><<<1024, 256, 0, stream>>>(x, tw, Tc, nullptr, out);
    }
}